// Round 21
// baseline (64.466 us; speedup 1.0000x reference)
//
#include <hip/hip_runtime.h>
#include <hip/hip_bf16.h>

typedef __attribute__((ext_vector_type(8))) short    s8v;  // bf16x8 (packing only)
typedef __attribute__((ext_vector_type(4))) short    s4v;  // bf16x4 MFMA-16 operand (2 VGPRs)
typedef __attribute__((ext_vector_type(4))) float    f4v;  // fp32x4 MFMA C/D
typedef __attribute__((ext_vector_type(4))) unsigned u4v;
typedef __attribute__((ext_vector_type(2))) unsigned u2v;

#define PIN(x) asm volatile("" : "+v"(x))

__device__ __forceinline__ unsigned short bfu(float x){
  union { __hip_bfloat16 h; unsigned short u; } cv;
  cv.h = __float2bfloat16(x);
  return cv.u;
}
__device__ __forceinline__ unsigned pkbf(float lo, float hi){
  return (unsigned)bfu(lo) | ((unsigned)bfu(hi) << 16);
}
__device__ __forceinline__ s8v mkfrag(unsigned a, unsigned b, unsigned c_, unsigned d){
  u4v u = {a, b, c_, d};
  return __builtin_bit_cast(s8v, u);
}
// 16x16x16 bf16 MFMA: 2-reg A/B — the packed D-quad (p0,p1) IS the B operand
// (identity k-mapping; A[c][k]=W[k][c], no row permutation).  Verified R19.
__device__ __forceinline__ f4v MM16(s4v a, s4v b, f4v acc){
  return __builtin_amdgcn_mfma_f32_16x16x16bf16_1k(a, b, acc, 0, 0, 0);
}

// Packed D-quad: p0 = (row 4g, 4g+1), p1 = (row 4g+2, 4g+3) at col c.
struct Pk { unsigned p0, p1; };
template<bool RELU>
__device__ __forceinline__ Pk mkpk(f4v d){
  float a = d[0], b = d[1], c_ = d[2], e = d[3];
  if (RELU){ a = fmaxf(a,0.f); b = fmaxf(b,0.f); c_ = fmaxf(c_,0.f); e = fmaxf(e,0.f); }
  Pk r; r.p0 = pkbf(a, b); r.p1 = pkbf(c_, e); return r;
}
__device__ __forceinline__ s4v pk2b(Pk x){
  u2v u = {x.p0, x.p1};
  return __builtin_bit_cast(s4v, u);          // free: D-quad -> B operand
}
__device__ __forceinline__ s4v mk2(unsigned a, unsigned b){
  u2v u = {a, b};
  return __builtin_bit_cast(s4v, u);
}

// LDS packing content IDENTICAL to R12/R17/R19 (proven).
__device__ __forceinline__ s8v loadA16(const float* __restrict__ W, int K, int c, int g,
                                       float scale = 1.0f){
  int r0 = 4*g;
  unsigned u0 = pkbf(r0+0<K ? W[(r0+0)*16+c]*scale : 0.f, r0+1<K ? W[(r0+1)*16+c]*scale : 0.f);
  unsigned u1 = pkbf(r0+2<K ? W[(r0+2)*16+c]*scale : 0.f, r0+3<K ? W[(r0+3)*16+c]*scale : 0.f);
  return mkfrag(u0, u1, 0u, 0u);
}
__device__ __forceinline__ s8v loadA32(const float* __restrict__ W, int c, int g){
  int r0 = 4*g;
  unsigned u0 = pkbf(W[(r0+0)*16+c],      W[(r0+1)*16+c]);
  unsigned u1 = pkbf(W[(r0+2)*16+c],      W[(r0+3)*16+c]);
  unsigned u2 = pkbf(W[(16+r0+0)*16+c],   W[(16+r0+1)*16+c]);
  unsigned u3 = pkbf(W[(16+r0+2)*16+c],   W[(16+r0+3)*16+c]);
  return mkfrag(u0, u1, u2, u3);
}

__device__ __forceinline__ void pl32(unsigned &a, unsigned &b){
  asm("v_permlane32_swap_b32 %0, %1" : "+v"(a), "+v"(b));
}
__device__ __forceinline__ void pl16(unsigned &a, unsigned &b){
  asm("v_permlane16_swap_b32 %0, %1" : "+v"(a), "+v"(b));
}
__device__ __forceinline__ float qsum(float part){
  unsigned pu = __builtin_bit_cast(unsigned, part), pv = pu;
  pl16(pu, pv);
  part = __builtin_bit_cast(float, pu) + __builtin_bit_cast(float, pv);
  pu = __builtin_bit_cast(unsigned, part); pv = pu;
  pl32(pu, pv);
  return __builtin_bit_cast(float, pu) + __builtin_bit_cast(float, pv);
}

// ---- LDS weight cache layout (bytes identical to R12..R19) ----
#define R16B  (11*512)          // 8B-fragment region: 11 frags x 64 lanes x 8B
#define RBB   (R16B + 4*1024)   // 16B-fragment region: 4 frags x 64 lanes x 16B
#define LDSZ  (RBB + 14*64)     // bias region: 14 vectors x 16 floats

// R21: 1024-thread blocks (16 waves/WG).  Hypothesis: occupancy has been
// pinned at ~18% regardless of grid (R19/R20) because the CU co-schedules
// only ~2 barrier-bearing WGs; bigger WGs deliver more waves per WG slot.
// launch_bounds(1024,4): k = 4*4/16 = 1 WG/CU min -> VGPR cap 128 (88 fits).
__global__ void __launch_bounds__(1024, 4) egnn_m16w(
    const float* __restrict__ nf,   const float* __restrict__ dist,
    const float* __restrict__ dz,   const float* __restrict__ s2p,
    const float* __restrict__ neW1, const float* __restrict__ neb1,
    const float* __restrict__ neW2, const float* __restrict__ neb2,
    const float* __restrict__ eeW1, const float* __restrict__ eeb1,
    const float* __restrict__ eeW2, const float* __restrict__ eeb2,
    const float* __restrict__ msgW1, const float* __restrict__ msgb1,
    const float* __restrict__ msgW2, const float* __restrict__ msgb2,
    const float* __restrict__ updW1, const float* __restrict__ updb1,
    const float* __restrict__ updW2, const float* __restrict__ updb2,
    const float* __restrict__ clsW1, const float* __restrict__ clsb1,
    const float* __restrict__ clsW2, const float* __restrict__ clsb2,
    float* __restrict__ out, int B, int niters, int nwaves)
{
  __shared__ __align__(16) char wl[LDSZ];
  const int tid  = threadIdx.x;
  const int lane = tid & 63;
  const int c = lane & 15;
  const int g = lane >> 4;

  // ---- one-time per-block weight packing into LDS (wave 0 only) ----
  if (tid < 64){
    auto st8 = [&](int j, s8v f){
      u4v u = __builtin_bit_cast(u4v, f);
      *reinterpret_cast<uint2*>(wl + j*512 + lane*8) = make_uint2(u[0], u[1]);
    };
    auto st16 = [&](int j, s8v f){
      *reinterpret_cast<u4v*>(wl + R16B + j*1024 + lane*16) = __builtin_bit_cast(u4v, f);
    };
    st8(0, loadA16(neW1,  2, c, g));
    st8(1, loadA16(neW2, 16, c, g));
    st8(2, loadA16(eeW1,  3, c, g));
    st8(3, loadA16(eeW2, 16, c, g));
    st8(4, loadA16(clsW1,16, c, g, 0.5f));       // fold node-mean 0.5
    #pragma unroll
    for (int l = 0; l < 2; ++l){
      st8(5+l,  loadA16(msgW1 + l*768 + 512, 16, c, g));  // ee rows 32..47
      st8(7+l,  loadA16(msgW2 + l*256, 16, c, g));
      st8(9+l,  loadA16(updW2 + l*256, 16, c, g));
      st16(l,   loadA32(msgW1 + l*768, c, g));            // concat rows 0..31
      st16(2+l, loadA32(updW1 + l*512, c, g));            // h rows, msg rows
    }
    if (lane < 16){
      float* bf = reinterpret_cast<float*>(wl + RBB);
      bf[ 0*16+lane] = neb1[lane];      bf[ 1*16+lane] = neb2[lane];
      bf[ 2*16+lane] = eeb1[lane];      bf[ 3*16+lane] = eeb2[lane];
      bf[ 4*16+lane] = clsb1[lane];
      bf[ 5*16+lane] = msgb1[lane];     bf[ 6*16+lane] = msgb1[16+lane];
      bf[ 7*16+lane] = msgb2[lane];     bf[ 8*16+lane] = msgb2[16+lane];
      bf[ 9*16+lane] = updb1[lane];     bf[10*16+lane] = updb1[16+lane];
      bf[11*16+lane] = updb2[lane];     bf[12*16+lane] = updb2[16+lane];
      bf[13*16+lane] = clsW2[lane];
    }
  }
  __syncthreads();

  const float cb2 = clsb2[0];          // wave-uniform -> SGPR
  const int gwave = blockIdx.x * 16 + (tid >> 6);   // 16 waves per block

  int it = gwave;
  float4 nfe[4]; float di[4], zz[4], sp[4];
  #pragma unroll
  for (int q = 0; q < 4; ++q){ nfe[q] = make_float4(0,0,0,0); di[q]=zz[q]=sp[q]=0.f; }
  if (it < niters){
    #pragma unroll
    for (int q = 0; q < 4; ++q){
      int e = min((4*it + q)*16 + c, B-1);
      nfe[q] = *reinterpret_cast<const float4*>(nf + (size_t)e * 4);
      di[q] = dist[e]; zz[q] = dz[e]; sp[q] = s2p[e];
    }
  }

  #pragma unroll 1
  for (; it < niters; it += nwaves){
    // PINned offsets: keep the weight/bias ds_reads in-loop (R8 spill trap).
    int o8 = lane*8, o16 = lane*16, ob = g*16;
    PIN(o8); PIN(o16); PIN(ob);
    const char* w8  = wl + o8;
    const char* w16 = wl + R16B + o16;
    const char* wb  = wl + RBB + ob;
    auto ld8 = [&](int j){                    // 2-reg A operand, direct
      uint2 v = *reinterpret_cast<const uint2*>(w8 + j*512);
      return mk2(v.x, v.y);
    };
    struct A32 { s4v lo, hi; };
    auto ld16 = [&](int j){                   // K=32 A: lo/hi 2-reg halves
      u4v v = *reinterpret_cast<const u4v*>(w16 + j*1024);
      A32 r; r.lo = mk2(v[0], v[1]); r.hi = mk2(v[2], v[3]);
      return r;
    };
    auto ldc = [&](int j){
      return *reinterpret_cast<const f4v*>(wb + j*64);
    };

    // prefetch next iteration's inputs
    float4 nfeN[4]; float diN[4], zzN[4], spN[4];
    #pragma unroll
    for (int q = 0; q < 4; ++q){ nfeN[q] = nfe[q]; diN[q]=di[q]; zzN[q]=zz[q]; spN[q]=sp[q]; }
    const int nit = it + nwaves;
    if (nit < niters){
      #pragma unroll
      for (int q = 0; q < 4; ++q){
        int e = min((4*nit + q)*16 + c, B-1);
        nfeN[q] = *reinterpret_cast<const float4*>(nf + (size_t)e * 4);
        diN[q] = dist[e]; zzN[q] = dz[e]; spN[q] = s2p[e];
      }
    }

    // ---- input fragments (g==0 masks REQUIRED — junk*0 = NaN when junk
    //      encodes Inf/NaN; R10 lesson) ----
    s4v b0f[4], b1f[4], bef[4];
    #pragma unroll
    for (int q = 0; q < 4; ++q){
      b0f[q] = mk2(g==0 ? pkbf(nfe[q].x, nfe[q].y) : 0u, 0u);
      b1f[q] = mk2(g==0 ? pkbf(nfe[q].z, nfe[q].w) : 0u, 0u);
      bef[q] = mk2(g==0 ? pkbf(di[q], zz[q]) : 0u, g==0 ? pkbf(sp[q], 0.f) : 0u);
    }

    // ---- embeddings ----
    f4v t0[4], t1[4], te[4], h0[4], h1[4], ee[4];
    { s4v A = ld8(0); f4v C = ldc(0);
      #pragma unroll
      for (int q = 0; q < 4; ++q){ t0[q] = MM16(A, b0f[q], C); t1[q] = MM16(A, b1f[q], C); } }
    { s4v A = ld8(2); f4v C = ldc(2);
      #pragma unroll
      for (int q = 0; q < 4; ++q){ te[q] = MM16(A, bef[q], C); } }
    { s4v A = ld8(1); f4v C = ldc(1);
      #pragma unroll
      for (int q = 0; q < 4; ++q){
        h0[q] = MM16(A, pk2b(mkpk<true>(t0[q])), C);
        h1[q] = MM16(A, pk2b(mkpk<true>(t1[q])), C); } }
    s4v eeB[4];
    { s4v A = ld8(3); f4v C = ldc(3);
      #pragma unroll
      for (int q = 0; q < 4; ++q){ ee[q] = MM16(A, pk2b(mkpk<true>(te[q])), C); } }
    #pragma unroll
    for (int q = 0; q < 4; ++q){ eeB[q] = pk2b(mkpk<false>(ee[q])); }

    // ---- eC HOIST (R17, proven): off the h-dependent critical chain ----
    f4v eC[2][4];
    #pragma unroll
    for (int l = 0; l < 2; ++l){
      s4v A = ld8(5+l); f4v C = ldc(5+l);
      #pragma unroll
      for (int q = 0; q < 4; ++q){ eC[l][q] = MM16(A, eeB[q], C); }
    }

    // ---- message-passing layers (K=32 = two chained MM16: hi·y + (lo·x + C)) ----
    #pragma unroll
    for (int l = 0; l < 2; ++l){
      s4v ph0[4], ph1[4];
      #pragma unroll
      for (int q = 0; q < 4; ++q){ ph0[q] = pk2b(mkpk<false>(h0[q])); ph1[q] = pk2b(mkpk<false>(h1[q])); }
      f4v m0[4], m1[4];
      { A32 A = ld16(l);
        #pragma unroll
        for (int q = 0; q < 4; ++q){
          m0[q] = MM16(A.hi, ph1[q], MM16(A.lo, ph0[q], eC[l][q]));
          m1[q] = MM16(A.hi, ph0[q], MM16(A.lo, ph1[q], eC[l][q])); } }
      f4v g0[4], g1[4];
      { s4v A = ld8(7+l); f4v C = ldc(7+l);
        #pragma unroll
        for (int q = 0; q < 4; ++q){
          g0[q] = MM16(A, pk2b(mkpk<true>(m0[q])), C);
          g1[q] = MM16(A, pk2b(mkpk<true>(m1[q])), C); } }
      f4v u0[4], u1[4];
      { A32 A = ld16(2+l); f4v C = ldc(9+l);
        #pragma unroll
        for (int q = 0; q < 4; ++q){
          u0[q] = MM16(A.hi, pk2b(mkpk<false>(g0[q])), MM16(A.lo, ph0[q], C));
          u1[q] = MM16(A.hi, pk2b(mkpk<false>(g1[q])), MM16(A.lo, ph1[q], C)); } }
      { s4v A = ld8(9+l); f4v C = ldc(11+l);
        #pragma unroll
        for (int q = 0; q < 4; ++q){
          h0[q] = h0[q] + MM16(A, pk2b(mkpk<true>(u0[q])), C);
          h1[q] = h1[q] + MM16(A, pk2b(mkpk<true>(u1[q])), C); } }
    }

    // ---- classifier (0.5 pre-folded into the aCl fragment) ----
    { s4v A = ld8(4); f4v C = ldc(4); f4v w2v = ldc(13);
      #pragma unroll
      for (int q = 0; q < 4; ++q){
        f4v tc = MM16(A, pk2b(mkpk<false>(h0[q] + h1[q])), C);
        float part = fmaxf(tc[0],0.f)*w2v[0] + fmaxf(tc[1],0.f)*w2v[1]
                   + fmaxf(tc[2],0.f)*w2v[2] + fmaxf(tc[3],0.f)*w2v[3];
        part = qsum(part);
        int e = (4*it + q)*16 + c;
        if (lane < 16 && e < B) out[e] = part + cb2;
      } }

    #pragma unroll
    for (int q = 0; q < 4; ++q){ nfe[q] = nfeN[q]; di[q]=diN[q]; zz[q]=zzN[q]; sp[q]=spN[q]; }
  }
}

extern "C" void kernel_launch(void* const* d_in, const int* in_sizes, int n_in,
                              void* d_out, int out_size, void* d_ws, size_t ws_size,
                              hipStream_t stream) {
  const float* nf    = (const float*)d_in[0];
  const float* dist  = (const float*)d_in[1];
  const float* dz    = (const float*)d_in[2];
  const float* s2p   = (const float*)d_in[3];
  const float* neW1  = (const float*)d_in[4];
  const float* neb1  = (const float*)d_in[5];
  const float* neW2  = (const float*)d_in[6];
  const float* neb2  = (const float*)d_in[7];
  const float* eeW1  = (const float*)d_in[8];
  const float* eeb1  = (const float*)d_in[9];
  const float* eeW2  = (const float*)d_in[10];
  const float* eeb2  = (const float*)d_in[11];
  const float* msgW1 = (const float*)d_in[12];
  const float* msgb1 = (const float*)d_in[13];
  const float* msgW2 = (const float*)d_in[14];
  const float* msgb2 = (const float*)d_in[15];
  const float* updW1 = (const float*)d_in[16];
  const float* updb1 = (const float*)d_in[17];
  const float* updW2 = (const float*)d_in[18];
  const float* updb2 = (const float*)d_in[19];
  const float* clsW1 = (const float*)d_in[20];
  const float* clsb1 = (const float*)d_in[21];
  const float* clsW2 = (const float*)d_in[22];
  const float* clsb2 = (const float*)d_in[23];

  const int B = in_sizes[1];
  const int ngroups = (B + 15) / 16;
  const int niters  = (ngroups + 3) / 4;       // 4 groups per wave-iteration
  // R21: 1024-thread blocks, 16 waves each, 4 iters/wave.
  // 256 blocks at B=1M (16384 iters = 256 x 16 x 4 exactly).
  int blocks = (niters + 63) / 64;
  if (blocks < 1) blocks = 1;
  const int nwaves = blocks * 16;

  egnn_m16w<<<blocks, 1024, 0, stream>>>(
      nf, dist, dz, s2p,
      neW1, neb1, neW2, neb2,
      eeW1, eeb1, eeW2, eeb2,
      msgW1, msgb1, msgW2, msgb2,
      updW1, updb1, updW2, updb2,
      clsW1, clsb1, clsW2, clsb2,
      (float*)d_out, B, niters, nwaves);
}

// Round 22
// 64.184 us; speedup vs baseline: 1.0044x; 1.0044x over previous
//
#include <hip/hip_runtime.h>
#include <hip/hip_bf16.h>

typedef __attribute__((ext_vector_type(8))) short    s8v;  // bf16x8 (packing only)
typedef __attribute__((ext_vector_type(4))) short    s4v;  // bf16x4 MFMA-16 operand (2 VGPRs)
typedef __attribute__((ext_vector_type(4))) float    f4v;  // fp32x4 MFMA C/D
typedef __attribute__((ext_vector_type(4))) unsigned u4v;
typedef __attribute__((ext_vector_type(2))) unsigned u2v;

#define PIN(x) asm volatile("" : "+v"(x))

__device__ __forceinline__ unsigned short bfu(float x){
  union { __hip_bfloat16 h; unsigned short u; } cv;
  cv.h = __float2bfloat16(x);
  return cv.u;
}
__device__ __forceinline__ unsigned pkbf(float lo, float hi){
  return (unsigned)bfu(lo) | ((unsigned)bfu(hi) << 16);
}
__device__ __forceinline__ s8v mkfrag(unsigned a, unsigned b, unsigned c_, unsigned d){
  u4v u = {a, b, c_, d};
  return __builtin_bit_cast(s8v, u);
}
// 16x16x16 bf16 MFMA: 2-reg A/B — the packed D-quad (p0,p1) IS the B operand
// (identity k-mapping; A[c][k]=W[k][c], no row permutation).  Verified R19.
__device__ __forceinline__ f4v MM16(s4v a, s4v b, f4v acc){
  return __builtin_amdgcn_mfma_f32_16x16x16bf16_1k(a, b, acc, 0, 0, 0);
}

// Packed D-quad: p0 = (row 4g, 4g+1), p1 = (row 4g+2, 4g+3) at col c.
struct Pk { unsigned p0, p1; };
template<bool RELU>
__device__ __forceinline__ Pk mkpk(f4v d){
  float a = d[0], b = d[1], c_ = d[2], e = d[3];
  if (RELU){ a = fmaxf(a,0.f); b = fmaxf(b,0.f); c_ = fmaxf(c_,0.f); e = fmaxf(e,0.f); }
  Pk r; r.p0 = pkbf(a, b); r.p1 = pkbf(c_, e); return r;
}
__device__ __forceinline__ s4v pk2b(Pk x){
  u2v u = {x.p0, x.p1};
  return __builtin_bit_cast(s4v, u);          // free: D-quad -> B operand
}
__device__ __forceinline__ s4v mk2(unsigned a, unsigned b){
  u2v u = {a, b};
  return __builtin_bit_cast(s4v, u);
}

// LDS packing content IDENTICAL to R12/R17/R19 (proven).
__device__ __forceinline__ s8v loadA16(const float* __restrict__ W, int K, int c, int g,
                                       float scale = 1.0f){
  int r0 = 4*g;
  unsigned u0 = pkbf(r0+0<K ? W[(r0+0)*16+c]*scale : 0.f, r0+1<K ? W[(r0+1)*16+c]*scale : 0.f);
  unsigned u1 = pkbf(r0+2<K ? W[(r0+2)*16+c]*scale : 0.f, r0+3<K ? W[(r0+3)*16+c]*scale : 0.f);
  return mkfrag(u0, u1, 0u, 0u);
}
__device__ __forceinline__ s8v loadA32(const float* __restrict__ W, int c, int g){
  int r0 = 4*g;
  unsigned u0 = pkbf(W[(r0+0)*16+c],      W[(r0+1)*16+c]);
  unsigned u1 = pkbf(W[(r0+2)*16+c],      W[(r0+3)*16+c]);
  unsigned u2 = pkbf(W[(16+r0+0)*16+c],   W[(16+r0+1)*16+c]);
  unsigned u3 = pkbf(W[(16+r0+2)*16+c],   W[(16+r0+3)*16+c]);
  return mkfrag(u0, u1, u2, u3);
}

__device__ __forceinline__ void pl32(unsigned &a, unsigned &b){
  asm("v_permlane32_swap_b32 %0, %1" : "+v"(a), "+v"(b));
}
__device__ __forceinline__ void pl16(unsigned &a, unsigned &b){
  asm("v_permlane16_swap_b32 %0, %1" : "+v"(a), "+v"(b));
}
__device__ __forceinline__ float qsum(float part){
  unsigned pu = __builtin_bit_cast(unsigned, part), pv = pu;
  pl16(pu, pv);
  part = __builtin_bit_cast(float, pu) + __builtin_bit_cast(float, pv);
  pu = __builtin_bit_cast(unsigned, part); pv = pu;
  pl32(pu, pv);
  return __builtin_bit_cast(float, pu) + __builtin_bit_cast(float, pv);
}

// ---- LDS weight cache layout (bytes identical to R12..R19) ----
#define R16B  (11*512)          // 8B-fragment region: 11 frags x 64 lanes x 8B
#define RBB   (R16B + 4*1024)   // 16B-fragment region: 4 frags x 64 lanes x 16B
#define LDSZ  (RBB + 14*64)     // bias region: 14 vectors x 16 floats

// R22: R21's 16-wave workgroups (occupancy 18->32%, WG-slot hypothesis
// CONFIRMED) but launch_bounds(1024,2): VGPR cap 256, same cap the proven
// 256-thread kernels ran at (allocator picked 88, no spill).  R21's (1024,4)
// forced VGPR=64 -> scratch spills (FETCH 14.5->32.5 MB) ate the gain.
__global__ void __launch_bounds__(1024, 2) egnn_m16w(
    const float* __restrict__ nf,   const float* __restrict__ dist,
    const float* __restrict__ dz,   const float* __restrict__ s2p,
    const float* __restrict__ neW1, const float* __restrict__ neb1,
    const float* __restrict__ neW2, const float* __restrict__ neb2,
    const float* __restrict__ eeW1, const float* __restrict__ eeb1,
    const float* __restrict__ eeW2, const float* __restrict__ eeb2,
    const float* __restrict__ msgW1, const float* __restrict__ msgb1,
    const float* __restrict__ msgW2, const float* __restrict__ msgb2,
    const float* __restrict__ updW1, const float* __restrict__ updb1,
    const float* __restrict__ updW2, const float* __restrict__ updb2,
    const float* __restrict__ clsW1, const float* __restrict__ clsb1,
    const float* __restrict__ clsW2, const float* __restrict__ clsb2,
    float* __restrict__ out, int B, int niters, int nwaves)
{
  __shared__ __align__(16) char wl[LDSZ];
  const int tid  = threadIdx.x;
  const int lane = tid & 63;
  const int c = lane & 15;
  const int g = lane >> 4;

  // ---- one-time per-block weight packing into LDS (wave 0 only) ----
  if (tid < 64){
    auto st8 = [&](int j, s8v f){
      u4v u = __builtin_bit_cast(u4v, f);
      *reinterpret_cast<uint2*>(wl + j*512 + lane*8) = make_uint2(u[0], u[1]);
    };
    auto st16 = [&](int j, s8v f){
      *reinterpret_cast<u4v*>(wl + R16B + j*1024 + lane*16) = __builtin_bit_cast(u4v, f);
    };
    st8(0, loadA16(neW1,  2, c, g));
    st8(1, loadA16(neW2, 16, c, g));
    st8(2, loadA16(eeW1,  3, c, g));
    st8(3, loadA16(eeW2, 16, c, g));
    st8(4, loadA16(clsW1,16, c, g, 0.5f));       // fold node-mean 0.5
    #pragma unroll
    for (int l = 0; l < 2; ++l){
      st8(5+l,  loadA16(msgW1 + l*768 + 512, 16, c, g));  // ee rows 32..47
      st8(7+l,  loadA16(msgW2 + l*256, 16, c, g));
      st8(9+l,  loadA16(updW2 + l*256, 16, c, g));
      st16(l,   loadA32(msgW1 + l*768, c, g));            // concat rows 0..31
      st16(2+l, loadA32(updW1 + l*512, c, g));            // h rows, msg rows
    }
    if (lane < 16){
      float* bf = reinterpret_cast<float*>(wl + RBB);
      bf[ 0*16+lane] = neb1[lane];      bf[ 1*16+lane] = neb2[lane];
      bf[ 2*16+lane] = eeb1[lane];      bf[ 3*16+lane] = eeb2[lane];
      bf[ 4*16+lane] = clsb1[lane];
      bf[ 5*16+lane] = msgb1[lane];     bf[ 6*16+lane] = msgb1[16+lane];
      bf[ 7*16+lane] = msgb2[lane];     bf[ 8*16+lane] = msgb2[16+lane];
      bf[ 9*16+lane] = updb1[lane];     bf[10*16+lane] = updb1[16+lane];
      bf[11*16+lane] = updb2[lane];     bf[12*16+lane] = updb2[16+lane];
      bf[13*16+lane] = clsW2[lane];
    }
  }
  __syncthreads();

  const float cb2 = clsb2[0];          // wave-uniform -> SGPR
  const int gwave = blockIdx.x * 16 + (tid >> 6);   // 16 waves per block

  int it = gwave;
  float4 nfe[4]; float di[4], zz[4], sp[4];
  #pragma unroll
  for (int q = 0; q < 4; ++q){ nfe[q] = make_float4(0,0,0,0); di[q]=zz[q]=sp[q]=0.f; }
  if (it < niters){
    #pragma unroll
    for (int q = 0; q < 4; ++q){
      int e = min((4*it + q)*16 + c, B-1);
      nfe[q] = *reinterpret_cast<const float4*>(nf + (size_t)e * 4);
      di[q] = dist[e]; zz[q] = dz[e]; sp[q] = s2p[e];
    }
  }

  #pragma unroll 1
  for (; it < niters; it += nwaves){
    // PINned offsets: keep the weight/bias ds_reads in-loop (R8 spill trap).
    int o8 = lane*8, o16 = lane*16, ob = g*16;
    PIN(o8); PIN(o16); PIN(ob);
    const char* w8  = wl + o8;
    const char* w16 = wl + R16B + o16;
    const char* wb  = wl + RBB + ob;
    auto ld8 = [&](int j){                    // 2-reg A operand, direct
      uint2 v = *reinterpret_cast<const uint2*>(w8 + j*512);
      return mk2(v.x, v.y);
    };
    struct A32 { s4v lo, hi; };
    auto ld16 = [&](int j){                   // K=32 A: lo/hi 2-reg halves
      u4v v = *reinterpret_cast<const u4v*>(w16 + j*1024);
      A32 r; r.lo = mk2(v[0], v[1]); r.hi = mk2(v[2], v[3]);
      return r;
    };
    auto ldc = [&](int j){
      return *reinterpret_cast<const f4v*>(wb + j*64);
    };

    // prefetch next iteration's inputs
    float4 nfeN[4]; float diN[4], zzN[4], spN[4];
    #pragma unroll
    for (int q = 0; q < 4; ++q){ nfeN[q] = nfe[q]; diN[q]=di[q]; zzN[q]=zz[q]; spN[q]=sp[q]; }
    const int nit = it + nwaves;
    if (nit < niters){
      #pragma unroll
      for (int q = 0; q < 4; ++q){
        int e = min((4*nit + q)*16 + c, B-1);
        nfeN[q] = *reinterpret_cast<const float4*>(nf + (size_t)e * 4);
        diN[q] = dist[e]; zzN[q] = dz[e]; spN[q] = s2p[e];
      }
    }

    // ---- input fragments (g==0 masks REQUIRED — junk*0 = NaN when junk
    //      encodes Inf/NaN; R10 lesson) ----
    s4v b0f[4], b1f[4], bef[4];
    #pragma unroll
    for (int q = 0; q < 4; ++q){
      b0f[q] = mk2(g==0 ? pkbf(nfe[q].x, nfe[q].y) : 0u, 0u);
      b1f[q] = mk2(g==0 ? pkbf(nfe[q].z, nfe[q].w) : 0u, 0u);
      bef[q] = mk2(g==0 ? pkbf(di[q], zz[q]) : 0u, g==0 ? pkbf(sp[q], 0.f) : 0u);
    }

    // ---- embeddings ----
    f4v t0[4], t1[4], te[4], h0[4], h1[4], ee[4];
    { s4v A = ld8(0); f4v C = ldc(0);
      #pragma unroll
      for (int q = 0; q < 4; ++q){ t0[q] = MM16(A, b0f[q], C); t1[q] = MM16(A, b1f[q], C); } }
    { s4v A = ld8(2); f4v C = ldc(2);
      #pragma unroll
      for (int q = 0; q < 4; ++q){ te[q] = MM16(A, bef[q], C); } }
    { s4v A = ld8(1); f4v C = ldc(1);
      #pragma unroll
      for (int q = 0; q < 4; ++q){
        h0[q] = MM16(A, pk2b(mkpk<true>(t0[q])), C);
        h1[q] = MM16(A, pk2b(mkpk<true>(t1[q])), C); } }
    s4v eeB[4];
    { s4v A = ld8(3); f4v C = ldc(3);
      #pragma unroll
      for (int q = 0; q < 4; ++q){ ee[q] = MM16(A, pk2b(mkpk<true>(te[q])), C); } }
    #pragma unroll
    for (int q = 0; q < 4; ++q){ eeB[q] = pk2b(mkpk<false>(ee[q])); }

    // ---- eC HOIST (R17, proven): off the h-dependent critical chain ----
    f4v eC[2][4];
    #pragma unroll
    for (int l = 0; l < 2; ++l){
      s4v A = ld8(5+l); f4v C = ldc(5+l);
      #pragma unroll
      for (int q = 0; q < 4; ++q){ eC[l][q] = MM16(A, eeB[q], C); }
    }

    // ---- message-passing layers (K=32 = two chained MM16: hi·y + (lo·x + C)) ----
    #pragma unroll
    for (int l = 0; l < 2; ++l){
      s4v ph0[4], ph1[4];
      #pragma unroll
      for (int q = 0; q < 4; ++q){ ph0[q] = pk2b(mkpk<false>(h0[q])); ph1[q] = pk2b(mkpk<false>(h1[q])); }
      f4v m0[4], m1[4];
      { A32 A = ld16(l);
        #pragma unroll
        for (int q = 0; q < 4; ++q){
          m0[q] = MM16(A.hi, ph1[q], MM16(A.lo, ph0[q], eC[l][q]));
          m1[q] = MM16(A.hi, ph0[q], MM16(A.lo, ph1[q], eC[l][q])); } }
      f4v g0[4], g1[4];
      { s4v A = ld8(7+l); f4v C = ldc(7+l);
        #pragma unroll
        for (int q = 0; q < 4; ++q){
          g0[q] = MM16(A, pk2b(mkpk<true>(m0[q])), C);
          g1[q] = MM16(A, pk2b(mkpk<true>(m1[q])), C); } }
      f4v u0[4], u1[4];
      { A32 A = ld16(2+l); f4v C = ldc(9+l);
        #pragma unroll
        for (int q = 0; q < 4; ++q){
          u0[q] = MM16(A.hi, pk2b(mkpk<false>(g0[q])), MM16(A.lo, ph0[q], C));
          u1[q] = MM16(A.hi, pk2b(mkpk<false>(g1[q])), MM16(A.lo, ph1[q], C)); } }
      { s4v A = ld8(9+l); f4v C = ldc(11+l);
        #pragma unroll
        for (int q = 0; q < 4; ++q){
          h0[q] = h0[q] + MM16(A, pk2b(mkpk<true>(u0[q])), C);
          h1[q] = h1[q] + MM16(A, pk2b(mkpk<true>(u1[q])), C); } }
    }

    // ---- classifier (0.5 pre-folded into the aCl fragment) ----
    { s4v A = ld8(4); f4v C = ldc(4); f4v w2v = ldc(13);
      #pragma unroll
      for (int q = 0; q < 4; ++q){
        f4v tc = MM16(A, pk2b(mkpk<false>(h0[q] + h1[q])), C);
        float part = fmaxf(tc[0],0.f)*w2v[0] + fmaxf(tc[1],0.f)*w2v[1]
                   + fmaxf(tc[2],0.f)*w2v[2] + fmaxf(tc[3],0.f)*w2v[3];
        part = qsum(part);
        int e = (4*it + q)*16 + c;
        if (lane < 16 && e < B) out[e] = part + cb2;
      } }

    #pragma unroll
    for (int q = 0; q < 4; ++q){ nfe[q] = nfeN[q]; di[q]=diN[q]; zz[q]=zzN[q]; sp[q]=spN[q]; }
  }
}

extern "C" void kernel_launch(void* const* d_in, const int* in_sizes, int n_in,
                              void* d_out, int out_size, void* d_ws, size_t ws_size,
                              hipStream_t stream) {
  const float* nf    = (const float*)d_in[0];
  const float* dist  = (const float*)d_in[1];
  const float* dz    = (const float*)d_in[2];
  const float* s2p   = (const float*)d_in[3];
  const float* neW1  = (const float*)d_in[4];
  const float* neb1  = (const float*)d_in[5];
  const float* neW2  = (const float*)d_in[6];
  const float* neb2  = (const float*)d_in[7];
  const float* eeW1  = (const float*)d_in[8];
  const float* eeb1  = (const float*)d_in[9];
  const float* eeW2  = (const float*)d_in[10];
  const float* eeb2  = (const float*)d_in[11];
  const float* msgW1 = (const float*)d_in[12];
  const float* msgb1 = (const float*)d_in[13];
  const float* msgW2 = (const float*)d_in[14];
  const float* msgb2 = (const float*)d_in[15];
  const float* updW1 = (const float*)d_in[16];
  const float* updb1 = (const float*)d_in[17];
  const float* updW2 = (const float*)d_in[18];
  const float* updb2 = (const float*)d_in[19];
  const float* clsW1 = (const float*)d_in[20];
  const float* clsb1 = (const float*)d_in[21];
  const float* clsW2 = (const float*)d_in[22];
  const float* clsb2 = (const float*)d_in[23];

  const int B = in_sizes[1];
  const int ngroups = (B + 15) / 16;
  const int niters  = (ngroups + 3) / 4;       // 4 groups per wave-iteration
  // 1024-thread blocks, 16 waves each, 4 iters/wave; 256 blocks at B=1M.
  int blocks = (niters + 63) / 64;
  if (blocks < 1) blocks = 1;
  const int nwaves = blocks * 16;

  egnn_m16w<<<blocks, 1024, 0, stream>>>(
      nf, dist, dz, s2p,
      neW1, neb1, neW2, neb2,
      eeW1, eeb1, eeW2, eeb2,
      msgW1, msgb1, msgW2, msgb2,
      updW1, updb1, updW2, updb2,
      clsW1, clsb1, clsW2, clsb2,
      (float*)d_out, B, niters, nwaves);
}

// Round 23
// 53.563 us; speedup vs baseline: 1.2035x; 1.1983x over previous
//
#include <hip/hip_runtime.h>
#include <hip/hip_bf16.h>

typedef __attribute__((ext_vector_type(8))) short    s8v;  // bf16x8 (packing only)
typedef __attribute__((ext_vector_type(4))) short    s4v;  // bf16x4 MFMA-16 operand (2 VGPRs)
typedef __attribute__((ext_vector_type(4))) float    f4v;  // fp32x4 MFMA C/D
typedef __attribute__((ext_vector_type(4))) unsigned u4v;
typedef __attribute__((ext_vector_type(2))) unsigned u2v;

#define PIN(x) asm volatile("" : "+v"(x))

__device__ __forceinline__ unsigned short bfu(float x){
  union { __hip_bfloat16 h; unsigned short u; } cv;
  cv.h = __float2bfloat16(x);
  return cv.u;
}
__device__ __forceinline__ unsigned pkbf(float lo, float hi){
  return (unsigned)bfu(lo) | ((unsigned)bfu(hi) << 16);
}
__device__ __forceinline__ s8v mkfrag(unsigned a, unsigned b, unsigned c_, unsigned d){
  u4v u = {a, b, c_, d};
  return __builtin_bit_cast(s8v, u);
}
// 16x16x16 bf16 MFMA: 2-reg A/B — the packed D-quad (p0,p1) IS the B operand
// (identity k-mapping; A[c][k]=W[k][c], no row permutation).  Verified R19.
__device__ __forceinline__ f4v MM16(s4v a, s4v b, f4v acc){
  return __builtin_amdgcn_mfma_f32_16x16x16bf16_1k(a, b, acc, 0, 0, 0);
}

// Packed D-quad: p0 = (row 4g, 4g+1), p1 = (row 4g+2, 4g+3) at col c.
struct Pk { unsigned p0, p1; };
template<bool RELU>
__device__ __forceinline__ Pk mkpk(f4v d){
  float a = d[0], b = d[1], c_ = d[2], e = d[3];
  if (RELU){ a = fmaxf(a,0.f); b = fmaxf(b,0.f); c_ = fmaxf(c_,0.f); e = fmaxf(e,0.f); }
  Pk r; r.p0 = pkbf(a, b); r.p1 = pkbf(c_, e); return r;
}
__device__ __forceinline__ s4v pk2b(Pk x){
  u2v u = {x.p0, x.p1};
  return __builtin_bit_cast(s4v, u);          // free: D-quad -> B operand
}
__device__ __forceinline__ s4v mk2(unsigned a, unsigned b){
  u2v u = {a, b};
  return __builtin_bit_cast(s4v, u);
}

// LDS packing content IDENTICAL to R12/R17/R19 (proven).
__device__ __forceinline__ s8v loadA16(const float* __restrict__ W, int K, int c, int g,
                                       float scale = 1.0f){
  int r0 = 4*g;
  unsigned u0 = pkbf(r0+0<K ? W[(r0+0)*16+c]*scale : 0.f, r0+1<K ? W[(r0+1)*16+c]*scale : 0.f);
  unsigned u1 = pkbf(r0+2<K ? W[(r0+2)*16+c]*scale : 0.f, r0+3<K ? W[(r0+3)*16+c]*scale : 0.f);
  return mkfrag(u0, u1, 0u, 0u);
}
__device__ __forceinline__ s8v loadA32(const float* __restrict__ W, int c, int g){
  int r0 = 4*g;
  unsigned u0 = pkbf(W[(r0+0)*16+c],      W[(r0+1)*16+c]);
  unsigned u1 = pkbf(W[(r0+2)*16+c],      W[(r0+3)*16+c]);
  unsigned u2 = pkbf(W[(16+r0+0)*16+c],   W[(16+r0+1)*16+c]);
  unsigned u3 = pkbf(W[(16+r0+2)*16+c],   W[(16+r0+3)*16+c]);
  return mkfrag(u0, u1, u2, u3);
}

__device__ __forceinline__ void pl32(unsigned &a, unsigned &b){
  asm("v_permlane32_swap_b32 %0, %1" : "+v"(a), "+v"(b));
}
__device__ __forceinline__ void pl16(unsigned &a, unsigned &b){
  asm("v_permlane16_swap_b32 %0, %1" : "+v"(a), "+v"(b));
}
__device__ __forceinline__ float qsum(float part){
  unsigned pu = __builtin_bit_cast(unsigned, part), pv = pu;
  pl16(pu, pv);
  part = __builtin_bit_cast(float, pu) + __builtin_bit_cast(float, pv);
  pu = __builtin_bit_cast(unsigned, part); pv = pu;
  pl32(pu, pv);
  return __builtin_bit_cast(float, pu) + __builtin_bit_cast(float, pv);
}

// ---- LDS weight cache layout (bytes identical to R12..R19) ----
#define R16B  (11*512)          // 8B-fragment region: 11 frags x 64 lanes x 8B
#define RBB   (R16B + 4*1024)   // 16B-fragment region: 4 frags x 64 lanes x 16B
#define LDSZ  (RBB + 14*64)     // bias region: 14 vectors x 16 floats

// R23: 512-thread WGs (8 waves).  R21/R22 confirmed the WG-slot occupancy
// mechanism (18->32%) but 1024-thread WGs force VGPR=64 (slot provisions a
// full WG in one 64k reg file) -> spill.  512 threads x 128 VGPR = 64k fits:
// compiler can keep our 88-VGPR working set spill-free while 2 WG slots
// deliver 16 waves/CU.
__global__ void __launch_bounds__(512, 2) egnn_m16h(
    const float* __restrict__ nf,   const float* __restrict__ dist,
    const float* __restrict__ dz,   const float* __restrict__ s2p,
    const float* __restrict__ neW1, const float* __restrict__ neb1,
    const float* __restrict__ neW2, const float* __restrict__ neb2,
    const float* __restrict__ eeW1, const float* __restrict__ eeb1,
    const float* __restrict__ eeW2, const float* __restrict__ eeb2,
    const float* __restrict__ msgW1, const float* __restrict__ msgb1,
    const float* __restrict__ msgW2, const float* __restrict__ msgb2,
    const float* __restrict__ updW1, const float* __restrict__ updb1,
    const float* __restrict__ updW2, const float* __restrict__ updb2,
    const float* __restrict__ clsW1, const float* __restrict__ clsb1,
    const float* __restrict__ clsW2, const float* __restrict__ clsb2,
    float* __restrict__ out, int B, int niters, int nwaves)
{
  __shared__ __align__(16) char wl[LDSZ];
  const int tid  = threadIdx.x;
  const int lane = tid & 63;
  const int c = lane & 15;
  const int g = lane >> 4;

  // ---- one-time per-block weight packing into LDS (wave 0 only) ----
  if (tid < 64){
    auto st8 = [&](int j, s8v f){
      u4v u = __builtin_bit_cast(u4v, f);
      *reinterpret_cast<uint2*>(wl + j*512 + lane*8) = make_uint2(u[0], u[1]);
    };
    auto st16 = [&](int j, s8v f){
      *reinterpret_cast<u4v*>(wl + R16B + j*1024 + lane*16) = __builtin_bit_cast(u4v, f);
    };
    st8(0, loadA16(neW1,  2, c, g));
    st8(1, loadA16(neW2, 16, c, g));
    st8(2, loadA16(eeW1,  3, c, g));
    st8(3, loadA16(eeW2, 16, c, g));
    st8(4, loadA16(clsW1,16, c, g, 0.5f));       // fold node-mean 0.5
    #pragma unroll
    for (int l = 0; l < 2; ++l){
      st8(5+l,  loadA16(msgW1 + l*768 + 512, 16, c, g));  // ee rows 32..47
      st8(7+l,  loadA16(msgW2 + l*256, 16, c, g));
      st8(9+l,  loadA16(updW2 + l*256, 16, c, g));
      st16(l,   loadA32(msgW1 + l*768, c, g));            // concat rows 0..31
      st16(2+l, loadA32(updW1 + l*512, c, g));            // h rows, msg rows
    }
    if (lane < 16){
      float* bf = reinterpret_cast<float*>(wl + RBB);
      bf[ 0*16+lane] = neb1[lane];      bf[ 1*16+lane] = neb2[lane];
      bf[ 2*16+lane] = eeb1[lane];      bf[ 3*16+lane] = eeb2[lane];
      bf[ 4*16+lane] = clsb1[lane];
      bf[ 5*16+lane] = msgb1[lane];     bf[ 6*16+lane] = msgb1[16+lane];
      bf[ 7*16+lane] = msgb2[lane];     bf[ 8*16+lane] = msgb2[16+lane];
      bf[ 9*16+lane] = updb1[lane];     bf[10*16+lane] = updb1[16+lane];
      bf[11*16+lane] = updb2[lane];     bf[12*16+lane] = updb2[16+lane];
      bf[13*16+lane] = clsW2[lane];
    }
  }
  __syncthreads();

  const float cb2 = clsb2[0];          // wave-uniform -> SGPR
  const int gwave = blockIdx.x * 8 + (tid >> 6);   // 8 waves per block

  int it = gwave;
  float4 nfe[4]; float di[4], zz[4], sp[4];
  #pragma unroll
  for (int q = 0; q < 4; ++q){ nfe[q] = make_float4(0,0,0,0); di[q]=zz[q]=sp[q]=0.f; }
  if (it < niters){
    #pragma unroll
    for (int q = 0; q < 4; ++q){
      int e = min((4*it + q)*16 + c, B-1);
      nfe[q] = *reinterpret_cast<const float4*>(nf + (size_t)e * 4);
      di[q] = dist[e]; zz[q] = dz[e]; sp[q] = s2p[e];
    }
  }

  #pragma unroll 1
  for (; it < niters; it += nwaves){
    // PINned offsets: keep the weight/bias ds_reads in-loop (R8 spill trap).
    int o8 = lane*8, o16 = lane*16, ob = g*16;
    PIN(o8); PIN(o16); PIN(ob);
    const char* w8  = wl + o8;
    const char* w16 = wl + R16B + o16;
    const char* wb  = wl + RBB + ob;
    auto ld8 = [&](int j){                    // 2-reg A operand, direct
      uint2 v = *reinterpret_cast<const uint2*>(w8 + j*512);
      return mk2(v.x, v.y);
    };
    struct A32 { s4v lo, hi; };
    auto ld16 = [&](int j){                   // K=32 A: lo/hi 2-reg halves
      u4v v = *reinterpret_cast<const u4v*>(w16 + j*1024);
      A32 r; r.lo = mk2(v[0], v[1]); r.hi = mk2(v[2], v[3]);
      return r;
    };
    auto ldc = [&](int j){
      return *reinterpret_cast<const f4v*>(wb + j*64);
    };

    // prefetch next iteration's inputs
    float4 nfeN[4]; float diN[4], zzN[4], spN[4];
    #pragma unroll
    for (int q = 0; q < 4; ++q){ nfeN[q] = nfe[q]; diN[q]=di[q]; zzN[q]=zz[q]; spN[q]=sp[q]; }
    const int nit = it + nwaves;
    if (nit < niters){
      #pragma unroll
      for (int q = 0; q < 4; ++q){
        int e = min((4*nit + q)*16 + c, B-1);
        nfeN[q] = *reinterpret_cast<const float4*>(nf + (size_t)e * 4);
        diN[q] = dist[e]; zzN[q] = dz[e]; spN[q] = s2p[e];
      }
    }

    // ---- input fragments (g==0 masks REQUIRED — junk*0 = NaN when junk
    //      encodes Inf/NaN; R10 lesson) ----
    s4v b0f[4], b1f[4], bef[4];
    #pragma unroll
    for (int q = 0; q < 4; ++q){
      b0f[q] = mk2(g==0 ? pkbf(nfe[q].x, nfe[q].y) : 0u, 0u);
      b1f[q] = mk2(g==0 ? pkbf(nfe[q].z, nfe[q].w) : 0u, 0u);
      bef[q] = mk2(g==0 ? pkbf(di[q], zz[q]) : 0u, g==0 ? pkbf(sp[q], 0.f) : 0u);
    }

    // ---- embeddings ----
    f4v t0[4], t1[4], te[4], h0[4], h1[4], ee[4];
    { s4v A = ld8(0); f4v C = ldc(0);
      #pragma unroll
      for (int q = 0; q < 4; ++q){ t0[q] = MM16(A, b0f[q], C); t1[q] = MM16(A, b1f[q], C); } }
    { s4v A = ld8(2); f4v C = ldc(2);
      #pragma unroll
      for (int q = 0; q < 4; ++q){ te[q] = MM16(A, bef[q], C); } }
    { s4v A = ld8(1); f4v C = ldc(1);
      #pragma unroll
      for (int q = 0; q < 4; ++q){
        h0[q] = MM16(A, pk2b(mkpk<true>(t0[q])), C);
        h1[q] = MM16(A, pk2b(mkpk<true>(t1[q])), C); } }
    s4v eeB[4];
    { s4v A = ld8(3); f4v C = ldc(3);
      #pragma unroll
      for (int q = 0; q < 4; ++q){ ee[q] = MM16(A, pk2b(mkpk<true>(te[q])), C); } }
    #pragma unroll
    for (int q = 0; q < 4; ++q){ eeB[q] = pk2b(mkpk<false>(ee[q])); }

    // ---- eC HOIST (R17, proven): off the h-dependent critical chain ----
    f4v eC[2][4];
    #pragma unroll
    for (int l = 0; l < 2; ++l){
      s4v A = ld8(5+l); f4v C = ldc(5+l);
      #pragma unroll
      for (int q = 0; q < 4; ++q){ eC[l][q] = MM16(A, eeB[q], C); }
    }

    // ---- message-passing layers (K=32 = two chained MM16: hi·y + (lo·x + C)) ----
    #pragma unroll
    for (int l = 0; l < 2; ++l){
      s4v ph0[4], ph1[4];
      #pragma unroll
      for (int q = 0; q < 4; ++q){ ph0[q] = pk2b(mkpk<false>(h0[q])); ph1[q] = pk2b(mkpk<false>(h1[q])); }
      f4v m0[4], m1[4];
      { A32 A = ld16(l);
        #pragma unroll
        for (int q = 0; q < 4; ++q){
          m0[q] = MM16(A.hi, ph1[q], MM16(A.lo, ph0[q], eC[l][q]));
          m1[q] = MM16(A.hi, ph0[q], MM16(A.lo, ph1[q], eC[l][q])); } }
      f4v g0[4], g1[4];
      { s4v A = ld8(7+l); f4v C = ldc(7+l);
        #pragma unroll
        for (int q = 0; q < 4; ++q){
          g0[q] = MM16(A, pk2b(mkpk<true>(m0[q])), C);
          g1[q] = MM16(A, pk2b(mkpk<true>(m1[q])), C); } }
      f4v u0[4], u1[4];
      { A32 A = ld16(2+l); f4v C = ldc(9+l);
        #pragma unroll
        for (int q = 0; q < 4; ++q){
          u0[q] = MM16(A.hi, pk2b(mkpk<false>(g0[q])), MM16(A.lo, ph0[q], C));
          u1[q] = MM16(A.hi, pk2b(mkpk<false>(g1[q])), MM16(A.lo, ph1[q], C)); } }
      { s4v A = ld8(9+l); f4v C = ldc(11+l);
        #pragma unroll
        for (int q = 0; q < 4; ++q){
          h0[q] = h0[q] + MM16(A, pk2b(mkpk<true>(u0[q])), C);
          h1[q] = h1[q] + MM16(A, pk2b(mkpk<true>(u1[q])), C); } }
    }

    // ---- classifier (0.5 pre-folded into the aCl fragment) ----
    { s4v A = ld8(4); f4v C = ldc(4); f4v w2v = ldc(13);
      #pragma unroll
      for (int q = 0; q < 4; ++q){
        f4v tc = MM16(A, pk2b(mkpk<false>(h0[q] + h1[q])), C);
        float part = fmaxf(tc[0],0.f)*w2v[0] + fmaxf(tc[1],0.f)*w2v[1]
                   + fmaxf(tc[2],0.f)*w2v[2] + fmaxf(tc[3],0.f)*w2v[3];
        part = qsum(part);
        int e = (4*it + q)*16 + c;
        if (lane < 16 && e < B) out[e] = part + cb2;
      } }

    #pragma unroll
    for (int q = 0; q < 4; ++q){ nfe[q] = nfeN[q]; di[q]=diN[q]; zz[q]=zzN[q]; sp[q]=spN[q]; }
  }
}

extern "C" void kernel_launch(void* const* d_in, const int* in_sizes, int n_in,
                              void* d_out, int out_size, void* d_ws, size_t ws_size,
                              hipStream_t stream) {
  const float* nf    = (const float*)d_in[0];
  const float* dist  = (const float*)d_in[1];
  const float* dz    = (const float*)d_in[2];
  const float* s2p   = (const float*)d_in[3];
  const float* neW1  = (const float*)d_in[4];
  const float* neb1  = (const float*)d_in[5];
  const float* neW2  = (const float*)d_in[6];
  const float* neb2  = (const float*)d_in[7];
  const float* eeW1  = (const float*)d_in[8];
  const float* eeb1  = (const float*)d_in[9];
  const float* eeW2  = (const float*)d_in[10];
  const float* eeb2  = (const float*)d_in[11];
  const float* msgW1 = (const float*)d_in[12];
  const float* msgb1 = (const float*)d_in[13];
  const float* msgW2 = (const float*)d_in[14];
  const float* msgb2 = (const float*)d_in[15];
  const float* updW1 = (const float*)d_in[16];
  const float* updb1 = (const float*)d_in[17];
  const float* updW2 = (const float*)d_in[18];
  const float* updb2 = (const float*)d_in[19];
  const float* clsW1 = (const float*)d_in[20];
  const float* clsb1 = (const float*)d_in[21];
  const float* clsW2 = (const float*)d_in[22];
  const float* clsb2 = (const float*)d_in[23];

  const int B = in_sizes[1];
  const int ngroups = (B + 15) / 16;
  const int niters  = (ngroups + 3) / 4;       // 4 groups per wave-iteration
  // 512-thread blocks, 8 waves each, 4 iters/wave; 512 blocks at B=1M.
  int blocks = (niters + 31) / 32;
  if (blocks < 1) blocks = 1;
  const int nwaves = blocks * 8;

  egnn_m16h<<<blocks, 512, 0, stream>>>(
      nf, dist, dz, s2p,
      neW1, neb1, neW2, neb2,
      eeW1, eeb1, eeW2, eeb2,
      msgW1, msgb1, msgW2, msgb2,
      updW1, updb1, updW2, updb2,
      clsW1, clsb1, clsW2, clsb2,
      (float*)d_out, B, niters, nwaves);
}

// Round 24
// 52.689 us; speedup vs baseline: 1.2235x; 1.0166x over previous
//
#include <hip/hip_runtime.h>
#include <hip/hip_bf16.h>

typedef __attribute__((ext_vector_type(8))) short    s8v;  // bf16x8 (packing only)
typedef __attribute__((ext_vector_type(4))) short    s4v;  // bf16x4 MFMA-16 operand (2 VGPRs)
typedef __attribute__((ext_vector_type(4))) float    f4v;  // fp32x4 MFMA C/D
typedef __attribute__((ext_vector_type(4))) unsigned u4v;
typedef __attribute__((ext_vector_type(2))) unsigned u2v;

#define PIN(x) asm volatile("" : "+v"(x))

__device__ __forceinline__ unsigned short bfu(float x){
  union { __hip_bfloat16 h; unsigned short u; } cv;
  cv.h = __float2bfloat16(x);
  return cv.u;
}
__device__ __forceinline__ unsigned pkbf(float lo, float hi){
  return (unsigned)bfu(lo) | ((unsigned)bfu(hi) << 16);
}
__device__ __forceinline__ s8v mkfrag(unsigned a, unsigned b, unsigned c_, unsigned d){
  u4v u = {a, b, c_, d};
  return __builtin_bit_cast(s8v, u);
}
// 16x16x16 bf16 MFMA: 2-reg A/B — the packed D-quad (p0,p1) IS the B operand
// (identity k-mapping; A[c][k]=W[k][c], no row permutation).  Verified R19.
__device__ __forceinline__ f4v MM16(s4v a, s4v b, f4v acc){
  return __builtin_amdgcn_mfma_f32_16x16x16bf16_1k(a, b, acc, 0, 0, 0);
}

// Packed D-quad: p0 = (row 4g, 4g+1), p1 = (row 4g+2, 4g+3) at col c.
struct Pk { unsigned p0, p1; };
template<bool RELU>
__device__ __forceinline__ Pk mkpk(f4v d){
  float a = d[0], b = d[1], c_ = d[2], e = d[3];
  if (RELU){ a = fmaxf(a,0.f); b = fmaxf(b,0.f); c_ = fmaxf(c_,0.f); e = fmaxf(e,0.f); }
  Pk r; r.p0 = pkbf(a, b); r.p1 = pkbf(c_, e); return r;
}
__device__ __forceinline__ s4v pk2b(Pk x){
  u2v u = {x.p0, x.p1};
  return __builtin_bit_cast(s4v, u);          // free: D-quad -> B operand
}
__device__ __forceinline__ s4v mk2(unsigned a, unsigned b){
  u2v u = {a, b};
  return __builtin_bit_cast(s4v, u);
}

// LDS packing content IDENTICAL to R12/R17/R19 (proven).
__device__ __forceinline__ s8v loadA16(const float* __restrict__ W, int K, int c, int g,
                                       float scale = 1.0f){
  int r0 = 4*g;
  unsigned u0 = pkbf(r0+0<K ? W[(r0+0)*16+c]*scale : 0.f, r0+1<K ? W[(r0+1)*16+c]*scale : 0.f);
  unsigned u1 = pkbf(r0+2<K ? W[(r0+2)*16+c]*scale : 0.f, r0+3<K ? W[(r0+3)*16+c]*scale : 0.f);
  return mkfrag(u0, u1, 0u, 0u);
}
__device__ __forceinline__ s8v loadA32(const float* __restrict__ W, int c, int g){
  int r0 = 4*g;
  unsigned u0 = pkbf(W[(r0+0)*16+c],      W[(r0+1)*16+c]);
  unsigned u1 = pkbf(W[(r0+2)*16+c],      W[(r0+3)*16+c]);
  unsigned u2 = pkbf(W[(16+r0+0)*16+c],   W[(16+r0+1)*16+c]);
  unsigned u3 = pkbf(W[(16+r0+2)*16+c],   W[(16+r0+3)*16+c]);
  return mkfrag(u0, u1, u2, u3);
}

__device__ __forceinline__ void pl32(unsigned &a, unsigned &b){
  asm("v_permlane32_swap_b32 %0, %1" : "+v"(a), "+v"(b));
}
__device__ __forceinline__ void pl16(unsigned &a, unsigned &b){
  asm("v_permlane16_swap_b32 %0, %1" : "+v"(a), "+v"(b));
}
__device__ __forceinline__ float qsum(float part){
  unsigned pu = __builtin_bit_cast(unsigned, part), pv = pu;
  pl16(pu, pv);
  part = __builtin_bit_cast(float, pu) + __builtin_bit_cast(float, pv);
  pu = __builtin_bit_cast(unsigned, part); pv = pu;
  pl32(pu, pv);
  return __builtin_bit_cast(float, pu) + __builtin_bit_cast(float, pv);
}

// ---- LDS weight cache layout (bytes identical to R12..R19) ----
#define R16B  (11*512)          // 8B-fragment region: 11 frags x 64 lanes x 8B
#define RBB   (R16B + 4*1024)   // 16B-fragment region: 4 frags x 64 lanes x 16B
#define LDSZ  (RBB + 14*64)     // bias region: 14 vectors x 16 floats

__global__ void __launch_bounds__(256, 2) egnn_m16(
    const float* __restrict__ nf,   const float* __restrict__ dist,
    const float* __restrict__ dz,   const float* __restrict__ s2p,
    const float* __restrict__ neW1, const float* __restrict__ neb1,
    const float* __restrict__ neW2, const float* __restrict__ neb2,
    const float* __restrict__ eeW1, const float* __restrict__ eeb1,
    const float* __restrict__ eeW2, const float* __restrict__ eeb2,
    const float* __restrict__ msgW1, const float* __restrict__ msgb1,
    const float* __restrict__ msgW2, const float* __restrict__ msgb2,
    const float* __restrict__ updW1, const float* __restrict__ updb1,
    const float* __restrict__ updW2, const float* __restrict__ updb2,
    const float* __restrict__ clsW1, const float* __restrict__ clsb1,
    const float* __restrict__ clsW2, const float* __restrict__ clsb2,
    float* __restrict__ out, int B, int niters, int nwaves)
{
  __shared__ __align__(16) char wl[LDSZ];
  const int tid  = threadIdx.x;
  const int lane = tid & 63;
  const int c = lane & 15;
  const int g = lane >> 4;

  // ---- one-time per-block weight packing into LDS (wave 0 only) ----
  if (tid < 64){
    auto st8 = [&](int j, s8v f){
      u4v u = __builtin_bit_cast(u4v, f);
      *reinterpret_cast<uint2*>(wl + j*512 + lane*8) = make_uint2(u[0], u[1]);
    };
    auto st16 = [&](int j, s8v f){
      *reinterpret_cast<u4v*>(wl + R16B + j*1024 + lane*16) = __builtin_bit_cast(u4v, f);
    };
    st8(0, loadA16(neW1,  2, c, g));
    st8(1, loadA16(neW2, 16, c, g));
    st8(2, loadA16(eeW1,  3, c, g));
    st8(3, loadA16(eeW2, 16, c, g));
    st8(4, loadA16(clsW1,16, c, g, 0.5f));       // fold node-mean 0.5
    #pragma unroll
    for (int l = 0; l < 2; ++l){
      st8(5+l,  loadA16(msgW1 + l*768 + 512, 16, c, g));  // ee rows 32..47
      st8(7+l,  loadA16(msgW2 + l*256, 16, c, g));
      st8(9+l,  loadA16(updW2 + l*256, 16, c, g));
      st16(l,   loadA32(msgW1 + l*768, c, g));            // concat rows 0..31
      st16(2+l, loadA32(updW1 + l*512, c, g));            // h rows, msg rows
    }
    if (lane < 16){
      float* bf = reinterpret_cast<float*>(wl + RBB);
      bf[ 0*16+lane] = neb1[lane];      bf[ 1*16+lane] = neb2[lane];
      bf[ 2*16+lane] = eeb1[lane];      bf[ 3*16+lane] = eeb2[lane];
      bf[ 4*16+lane] = clsb1[lane];
      bf[ 5*16+lane] = msgb1[lane];     bf[ 6*16+lane] = msgb1[16+lane];
      bf[ 7*16+lane] = msgb2[lane];     bf[ 8*16+lane] = msgb2[16+lane];
      bf[ 9*16+lane] = updb1[lane];     bf[10*16+lane] = updb1[16+lane];
      bf[11*16+lane] = updb2[lane];     bf[12*16+lane] = updb2[16+lane];
      bf[13*16+lane] = clsW2[lane];
    }
  }
  __syncthreads();

  const float cb2 = clsb2[0];          // wave-uniform -> SGPR
  const int gwave = blockIdx.x * 4 + (tid >> 6);

  int it = gwave;
  float4 nfe[4]; float di[4], zz[4], sp[4];
  #pragma unroll
  for (int q = 0; q < 4; ++q){ nfe[q] = make_float4(0,0,0,0); di[q]=zz[q]=sp[q]=0.f; }
  if (it < niters){
    #pragma unroll
    for (int q = 0; q < 4; ++q){
      int e = min((4*it + q)*16 + c, B-1);
      nfe[q] = *reinterpret_cast<const float4*>(nf + (size_t)e * 4);
      di[q] = dist[e]; zz[q] = dz[e]; sp[q] = s2p[e];
    }
  }

  #pragma unroll 1
  for (; it < niters; it += nwaves){
    // PINned offsets: keep the weight/bias ds_reads in-loop (R8 spill trap).
    int o8 = lane*8, o16 = lane*16, ob = g*16;
    PIN(o8); PIN(o16); PIN(ob);
    const char* w8  = wl + o8;
    const char* w16 = wl + R16B + o16;
    const char* wb  = wl + RBB + ob;
    auto ld8 = [&](int j){                    // 2-reg A operand, direct
      uint2 v = *reinterpret_cast<const uint2*>(w8 + j*512);
      return mk2(v.x, v.y);
    };
    struct A32 { s4v lo, hi; };
    auto ld16 = [&](int j){                   // K=32 A: lo/hi 2-reg halves
      u4v v = *reinterpret_cast<const u4v*>(w16 + j*1024);
      A32 r; r.lo = mk2(v[0], v[1]); r.hi = mk2(v[2], v[3]);
      return r;
    };
    auto ldc = [&](int j){
      return *reinterpret_cast<const f4v*>(wb + j*64);
    };

    // prefetch next iteration's inputs
    float4 nfeN[4]; float diN[4], zzN[4], spN[4];
    #pragma unroll
    for (int q = 0; q < 4; ++q){ nfeN[q] = nfe[q]; diN[q]=di[q]; zzN[q]=zz[q]; spN[q]=sp[q]; }
    const int nit = it + nwaves;
    if (nit < niters){
      #pragma unroll
      for (int q = 0; q < 4; ++q){
        int e = min((4*nit + q)*16 + c, B-1);
        nfeN[q] = *reinterpret_cast<const float4*>(nf + (size_t)e * 4);
        diN[q] = dist[e]; zzN[q] = dz[e]; spN[q] = s2p[e];
      }
    }

    // ---- input fragments (g==0 masks REQUIRED — junk*0 = NaN when junk
    //      encodes Inf/NaN; R10 lesson) ----
    s4v b0f[4], b1f[4], bef[4];
    #pragma unroll
    for (int q = 0; q < 4; ++q){
      b0f[q] = mk2(g==0 ? pkbf(nfe[q].x, nfe[q].y) : 0u, 0u);
      b1f[q] = mk2(g==0 ? pkbf(nfe[q].z, nfe[q].w) : 0u, 0u);
      bef[q] = mk2(g==0 ? pkbf(di[q], zz[q]) : 0u, g==0 ? pkbf(sp[q], 0.f) : 0u);
    }

    // ---- embeddings ----
    f4v t0[4], t1[4], te[4], h0[4], h1[4], ee[4];
    { s4v A = ld8(0); f4v C = ldc(0);
      #pragma unroll
      for (int q = 0; q < 4; ++q){ t0[q] = MM16(A, b0f[q], C); t1[q] = MM16(A, b1f[q], C); } }
    { s4v A = ld8(2); f4v C = ldc(2);
      #pragma unroll
      for (int q = 0; q < 4; ++q){ te[q] = MM16(A, bef[q], C); } }
    { s4v A = ld8(1); f4v C = ldc(1);
      #pragma unroll
      for (int q = 0; q < 4; ++q){
        h0[q] = MM16(A, pk2b(mkpk<true>(t0[q])), C);
        h1[q] = MM16(A, pk2b(mkpk<true>(t1[q])), C); } }
    s4v eeB[4];
    { s4v A = ld8(3); f4v C = ldc(3);
      #pragma unroll
      for (int q = 0; q < 4; ++q){ ee[q] = MM16(A, pk2b(mkpk<true>(te[q])), C); } }
    #pragma unroll
    for (int q = 0; q < 4; ++q){ eeB[q] = pk2b(mkpk<false>(ee[q])); }

    // ---- eC HOIST (R17, proven): off the h-dependent critical chain ----
    f4v eC[2][4];
    #pragma unroll
    for (int l = 0; l < 2; ++l){
      s4v A = ld8(5+l); f4v C = ldc(5+l);
      #pragma unroll
      for (int q = 0; q < 4; ++q){ eC[l][q] = MM16(A, eeB[q], C); }
    }

    // ---- message-passing layers (K=32 = two chained MM16: hi·y + (lo·x + C)) ----
    #pragma unroll
    for (int l = 0; l < 2; ++l){
      s4v ph0[4], ph1[4];
      #pragma unroll
      for (int q = 0; q < 4; ++q){ ph0[q] = pk2b(mkpk<false>(h0[q])); ph1[q] = pk2b(mkpk<false>(h1[q])); }
      f4v m0[4], m1[4];
      { A32 A = ld16(l);
        #pragma unroll
        for (int q = 0; q < 4; ++q){
          m0[q] = MM16(A.hi, ph1[q], MM16(A.lo, ph0[q], eC[l][q]));
          m1[q] = MM16(A.hi, ph0[q], MM16(A.lo, ph1[q], eC[l][q])); } }
      f4v g0[4], g1[4];
      { s4v A = ld8(7+l); f4v C = ldc(7+l);
        #pragma unroll
        for (int q = 0; q < 4; ++q){
          g0[q] = MM16(A, pk2b(mkpk<true>(m0[q])), C);
          g1[q] = MM16(A, pk2b(mkpk<true>(m1[q])), C); } }
      f4v u0[4], u1[4];
      { A32 A = ld16(2+l); f4v C = ldc(9+l);
        #pragma unroll
        for (int q = 0; q < 4; ++q){
          u0[q] = MM16(A.hi, pk2b(mkpk<false>(g0[q])), MM16(A.lo, ph0[q], C));
          u1[q] = MM16(A.hi, pk2b(mkpk<false>(g1[q])), MM16(A.lo, ph1[q], C)); } }
      { s4v A = ld8(9+l); f4v C = ldc(11+l);
        #pragma unroll
        for (int q = 0; q < 4; ++q){
          h0[q] = h0[q] + MM16(A, pk2b(mkpk<true>(u0[q])), C);
          h1[q] = h1[q] + MM16(A, pk2b(mkpk<true>(u1[q])), C); } }
    }

    // ---- classifier (0.5 pre-folded into the aCl fragment) ----
    { s4v A = ld8(4); f4v C = ldc(4); f4v w2v = ldc(13);
      #pragma unroll
      for (int q = 0; q < 4; ++q){
        f4v tc = MM16(A, pk2b(mkpk<false>(h0[q] + h1[q])), C);
        float part = fmaxf(tc[0],0.f)*w2v[0] + fmaxf(tc[1],0.f)*w2v[1]
                   + fmaxf(tc[2],0.f)*w2v[2] + fmaxf(tc[3],0.f)*w2v[3];
        part = qsum(part);
        int e = (4*it + q)*16 + c;
        if (lane < 16 && e < B) out[e] = part + cb2;
      } }

    #pragma unroll
    for (int q = 0; q < 4; ++q){ nfe[q] = nfeN[q]; di[q]=diN[q]; zz[q]=zzN[q]; sp[q]=spN[q]; }
  }
}

extern "C" void kernel_launch(void* const* d_in, const int* in_sizes, int n_in,
                              void* d_out, int out_size, void* d_ws, size_t ws_size,
                              hipStream_t stream) {
  const float* nf    = (const float*)d_in[0];
  const float* dist  = (const float*)d_in[1];
  const float* dz    = (const float*)d_in[2];
  const float* s2p   = (const float*)d_in[3];
  const float* neW1  = (const float*)d_in[4];
  const float* neb1  = (const float*)d_in[5];
  const float* neW2  = (const float*)d_in[6];
  const float* neb2  = (const float*)d_in[7];
  const float* eeW1  = (const float*)d_in[8];
  const float* eeb1  = (const float*)d_in[9];
  const float* eeW2  = (const float*)d_in[10];
  const float* eeb2  = (const float*)d_in[11];
  const float* msgW1 = (const float*)d_in[12];
  const float* msgb1 = (const float*)d_in[13];
  const float* msgW2 = (const float*)d_in[14];
  const float* msgb2 = (const float*)d_in[15];
  const float* updW1 = (const float*)d_in[16];
  const float* updb1 = (const float*)d_in[17];
  const float* updW2 = (const float*)d_in[18];
  const float* updb2 = (const float*)d_in[19];
  const float* clsW1 = (const float*)d_in[20];
  const float* clsb1 = (const float*)d_in[21];
  const float* clsW2 = (const float*)d_in[22];
  const float* clsb2 = (const float*)d_in[23];

  const int B = in_sizes[1];
  const int ngroups = (B + 15) / 16;
  const int niters  = (ngroups + 3) / 4;       // 4 groups per wave-iteration
  // R24: ONLY change vs R19 — blocks 1024 -> 512 (8 iters/wave).  Completes
  // the config sweep along the monotone fewer-blocks-better trend (prologue
  // amortization + 87.5% prefetch coverage).
  int blocks = 512;
  if (blocks * 4 > niters) blocks = (niters + 3) / 4;
  const int nwaves = blocks * 4;

  egnn_m16<<<blocks, 256, 0, stream>>>(
      nf, dist, dz, s2p,
      neW1, neb1, neW2, neb2,
      eeW1, eeb1, eeW2, eeb2,
      msgW1, msgb1, msgW2, msgb2,
      updW1, updb1, updW2, updb2,
      clsW1, clsb1, clsW2, clsb2,
      (float*)d_out, B, niters, nwaves);
}

// Round 25
// 52.421 us; speedup vs baseline: 1.2298x; 1.0051x over previous
//
#include <hip/hip_runtime.h>
#include <hip/hip_bf16.h>

typedef __attribute__((ext_vector_type(8))) short    s8v;  // bf16x8 (packing only)
typedef __attribute__((ext_vector_type(4))) short    s4v;  // bf16x4 MFMA-16 operand (2 VGPRs)
typedef __attribute__((ext_vector_type(4))) float    f4v;  // fp32x4 MFMA C/D
typedef __attribute__((ext_vector_type(4))) unsigned u4v;
typedef __attribute__((ext_vector_type(2))) unsigned u2v;

#define PIN(x) asm volatile("" : "+v"(x))
#define QN 6   // R25: ILP width 4 -> 6 (same edit class as R12's proven 2->4)

__device__ __forceinline__ unsigned short bfu(float x){
  union { __hip_bfloat16 h; unsigned short u; } cv;
  cv.h = __float2bfloat16(x);
  return cv.u;
}
__device__ __forceinline__ unsigned pkbf(float lo, float hi){
  return (unsigned)bfu(lo) | ((unsigned)bfu(hi) << 16);
}
__device__ __forceinline__ s8v mkfrag(unsigned a, unsigned b, unsigned c_, unsigned d){
  u4v u = {a, b, c_, d};
  return __builtin_bit_cast(s8v, u);
}
// 16x16x16 bf16 MFMA: 2-reg A/B — the packed D-quad (p0,p1) IS the B operand
// (identity k-mapping; A[c][k]=W[k][c], no row permutation).  Verified R19.
__device__ __forceinline__ f4v MM16(s4v a, s4v b, f4v acc){
  return __builtin_amdgcn_mfma_f32_16x16x16bf16_1k(a, b, acc, 0, 0, 0);
}

// Packed D-quad: p0 = (row 4g, 4g+1), p1 = (row 4g+2, 4g+3) at col c.
struct Pk { unsigned p0, p1; };
template<bool RELU>
__device__ __forceinline__ Pk mkpk(f4v d){
  float a = d[0], b = d[1], c_ = d[2], e = d[3];
  if (RELU){ a = fmaxf(a,0.f); b = fmaxf(b,0.f); c_ = fmaxf(c_,0.f); e = fmaxf(e,0.f); }
  Pk r; r.p0 = pkbf(a, b); r.p1 = pkbf(c_, e); return r;
}
__device__ __forceinline__ s4v pk2b(Pk x){
  u2v u = {x.p0, x.p1};
  return __builtin_bit_cast(s4v, u);          // free: D-quad -> B operand
}
__device__ __forceinline__ s4v mk2(unsigned a, unsigned b){
  u2v u = {a, b};
  return __builtin_bit_cast(s4v, u);
}

// LDS packing content IDENTICAL to R12/R17/R19 (proven).
__device__ __forceinline__ s8v loadA16(const float* __restrict__ W, int K, int c, int g,
                                       float scale = 1.0f){
  int r0 = 4*g;
  unsigned u0 = pkbf(r0+0<K ? W[(r0+0)*16+c]*scale : 0.f, r0+1<K ? W[(r0+1)*16+c]*scale : 0.f);
  unsigned u1 = pkbf(r0+2<K ? W[(r0+2)*16+c]*scale : 0.f, r0+3<K ? W[(r0+3)*16+c]*scale : 0.f);
  return mkfrag(u0, u1, 0u, 0u);
}
__device__ __forceinline__ s8v loadA32(const float* __restrict__ W, int c, int g){
  int r0 = 4*g;
  unsigned u0 = pkbf(W[(r0+0)*16+c],      W[(r0+1)*16+c]);
  unsigned u1 = pkbf(W[(r0+2)*16+c],      W[(r0+3)*16+c]);
  unsigned u2 = pkbf(W[(16+r0+0)*16+c],   W[(16+r0+1)*16+c]);
  unsigned u3 = pkbf(W[(16+r0+2)*16+c],   W[(16+r0+3)*16+c]);
  return mkfrag(u0, u1, u2, u3);
}

__device__ __forceinline__ void pl32(unsigned &a, unsigned &b){
  asm("v_permlane32_swap_b32 %0, %1" : "+v"(a), "+v"(b));
}
__device__ __forceinline__ void pl16(unsigned &a, unsigned &b){
  asm("v_permlane16_swap_b32 %0, %1" : "+v"(a), "+v"(b));
}
__device__ __forceinline__ float qsum(float part){
  unsigned pu = __builtin_bit_cast(unsigned, part), pv = pu;
  pl16(pu, pv);
  part = __builtin_bit_cast(float, pu) + __builtin_bit_cast(float, pv);
  pu = __builtin_bit_cast(unsigned, part); pv = pu;
  pl32(pu, pv);
  return __builtin_bit_cast(float, pu) + __builtin_bit_cast(float, pv);
}

// ---- LDS weight cache layout (bytes identical to R12..R19) ----
#define R16B  (11*512)          // 8B-fragment region: 11 frags x 64 lanes x 8B
#define RBB   (R16B + 4*1024)   // 16B-fragment region: 4 frags x 64 lanes x 16B
#define LDSZ  (RBB + 14*64)     // bias region: 14 vectors x 16 floats

__global__ void __launch_bounds__(256, 2) egnn_i6(
    const float* __restrict__ nf,   const float* __restrict__ dist,
    const float* __restrict__ dz,   const float* __restrict__ s2p,
    const float* __restrict__ neW1, const float* __restrict__ neb1,
    const float* __restrict__ neW2, const float* __restrict__ neb2,
    const float* __restrict__ eeW1, const float* __restrict__ eeb1,
    const float* __restrict__ eeW2, const float* __restrict__ eeb2,
    const float* __restrict__ msgW1, const float* __restrict__ msgb1,
    const float* __restrict__ msgW2, const float* __restrict__ msgb2,
    const float* __restrict__ updW1, const float* __restrict__ updb1,
    const float* __restrict__ updW2, const float* __restrict__ updb2,
    const float* __restrict__ clsW1, const float* __restrict__ clsb1,
    const float* __restrict__ clsW2, const float* __restrict__ clsb2,
    float* __restrict__ out, int B, int niters, int nwaves)
{
  __shared__ __align__(16) char wl[LDSZ];
  const int tid  = threadIdx.x;
  const int lane = tid & 63;
  const int c = lane & 15;
  const int g = lane >> 4;

  // ---- one-time per-block weight packing into LDS (wave 0 only) ----
  if (tid < 64){
    auto st8 = [&](int j, s8v f){
      u4v u = __builtin_bit_cast(u4v, f);
      *reinterpret_cast<uint2*>(wl + j*512 + lane*8) = make_uint2(u[0], u[1]);
    };
    auto st16 = [&](int j, s8v f){
      *reinterpret_cast<u4v*>(wl + R16B + j*1024 + lane*16) = __builtin_bit_cast(u4v, f);
    };
    st8(0, loadA16(neW1,  2, c, g));
    st8(1, loadA16(neW2, 16, c, g));
    st8(2, loadA16(eeW1,  3, c, g));
    st8(3, loadA16(eeW2, 16, c, g));
    st8(4, loadA16(clsW1,16, c, g, 0.5f));       // fold node-mean 0.5
    #pragma unroll
    for (int l = 0; l < 2; ++l){
      st8(5+l,  loadA16(msgW1 + l*768 + 512, 16, c, g));  // ee rows 32..47
      st8(7+l,  loadA16(msgW2 + l*256, 16, c, g));
      st8(9+l,  loadA16(updW2 + l*256, 16, c, g));
      st16(l,   loadA32(msgW1 + l*768, c, g));            // concat rows 0..31
      st16(2+l, loadA32(updW1 + l*512, c, g));            // h rows, msg rows
    }
    if (lane < 16){
      float* bf = reinterpret_cast<float*>(wl + RBB);
      bf[ 0*16+lane] = neb1[lane];      bf[ 1*16+lane] = neb2[lane];
      bf[ 2*16+lane] = eeb1[lane];      bf[ 3*16+lane] = eeb2[lane];
      bf[ 4*16+lane] = clsb1[lane];
      bf[ 5*16+lane] = msgb1[lane];     bf[ 6*16+lane] = msgb1[16+lane];
      bf[ 7*16+lane] = msgb2[lane];     bf[ 8*16+lane] = msgb2[16+lane];
      bf[ 9*16+lane] = updb1[lane];     bf[10*16+lane] = updb1[16+lane];
      bf[11*16+lane] = updb2[lane];     bf[12*16+lane] = updb2[16+lane];
      bf[13*16+lane] = clsW2[lane];
    }
  }
  __syncthreads();

  const float cb2 = clsb2[0];          // wave-uniform -> SGPR
  const int gwave = blockIdx.x * 4 + (tid >> 6);

  int it = gwave;
  float4 nfe[QN]; float di[QN], zz[QN], sp[QN];
  #pragma unroll
  for (int q = 0; q < QN; ++q){ nfe[q] = make_float4(0,0,0,0); di[q]=zz[q]=sp[q]=0.f; }
  if (it < niters){
    #pragma unroll
    for (int q = 0; q < QN; ++q){
      int e = min((QN*it + q)*16 + c, B-1);
      nfe[q] = *reinterpret_cast<const float4*>(nf + (size_t)e * 4);
      di[q] = dist[e]; zz[q] = dz[e]; sp[q] = s2p[e];
    }
  }

  #pragma unroll 1
  for (; it < niters; it += nwaves){
    // PINned offsets: keep the weight/bias ds_reads in-loop (R8 spill trap).
    int o8 = lane*8, o16 = lane*16, ob = g*16;
    PIN(o8); PIN(o16); PIN(ob);
    const char* w8  = wl + o8;
    const char* w16 = wl + R16B + o16;
    const char* wb  = wl + RBB + ob;
    auto ld8 = [&](int j){                    // 2-reg A operand, direct
      uint2 v = *reinterpret_cast<const uint2*>(w8 + j*512);
      return mk2(v.x, v.y);
    };
    struct A32 { s4v lo, hi; };
    auto ld16 = [&](int j){                   // K=32 A: lo/hi 2-reg halves
      u4v v = *reinterpret_cast<const u4v*>(w16 + j*1024);
      A32 r; r.lo = mk2(v[0], v[1]); r.hi = mk2(v[2], v[3]);
      return r;
    };
    auto ldc = [&](int j){
      return *reinterpret_cast<const f4v*>(wb + j*64);
    };

    // prefetch next iteration's inputs
    float4 nfeN[QN]; float diN[QN], zzN[QN], spN[QN];
    #pragma unroll
    for (int q = 0; q < QN; ++q){ nfeN[q] = nfe[q]; diN[q]=di[q]; zzN[q]=zz[q]; spN[q]=sp[q]; }
    const int nit = it + nwaves;
    if (nit < niters){
      #pragma unroll
      for (int q = 0; q < QN; ++q){
        int e = min((QN*nit + q)*16 + c, B-1);
        nfeN[q] = *reinterpret_cast<const float4*>(nf + (size_t)e * 4);
        diN[q] = dist[e]; zzN[q] = dz[e]; spN[q] = s2p[e];
      }
    }

    // ---- input fragments (g==0 masks REQUIRED — junk*0 = NaN when junk
    //      encodes Inf/NaN; R10 lesson) ----
    s4v b0f[QN], b1f[QN], bef[QN];
    #pragma unroll
    for (int q = 0; q < QN; ++q){
      b0f[q] = mk2(g==0 ? pkbf(nfe[q].x, nfe[q].y) : 0u, 0u);
      b1f[q] = mk2(g==0 ? pkbf(nfe[q].z, nfe[q].w) : 0u, 0u);
      bef[q] = mk2(g==0 ? pkbf(di[q], zz[q]) : 0u, g==0 ? pkbf(sp[q], 0.f) : 0u);
    }

    // ---- embeddings ----
    f4v t0[QN], t1[QN], te[QN], h0[QN], h1[QN], ee[QN];
    { s4v A = ld8(0); f4v C = ldc(0);
      #pragma unroll
      for (int q = 0; q < QN; ++q){ t0[q] = MM16(A, b0f[q], C); t1[q] = MM16(A, b1f[q], C); } }
    { s4v A = ld8(2); f4v C = ldc(2);
      #pragma unroll
      for (int q = 0; q < QN; ++q){ te[q] = MM16(A, bef[q], C); } }
    { s4v A = ld8(1); f4v C = ldc(1);
      #pragma unroll
      for (int q = 0; q < QN; ++q){
        h0[q] = MM16(A, pk2b(mkpk<true>(t0[q])), C);
        h1[q] = MM16(A, pk2b(mkpk<true>(t1[q])), C); } }
    s4v eeB[QN];
    { s4v A = ld8(3); f4v C = ldc(3);
      #pragma unroll
      for (int q = 0; q < QN; ++q){ ee[q] = MM16(A, pk2b(mkpk<true>(te[q])), C); } }
    #pragma unroll
    for (int q = 0; q < QN; ++q){ eeB[q] = pk2b(mkpk<false>(ee[q])); }

    // ---- eC HOIST (R17, proven): off the h-dependent critical chain ----
    f4v eC[2][QN];
    #pragma unroll
    for (int l = 0; l < 2; ++l){
      s4v A = ld8(5+l); f4v C = ldc(5+l);
      #pragma unroll
      for (int q = 0; q < QN; ++q){ eC[l][q] = MM16(A, eeB[q], C); }
    }

    // ---- message-passing layers (K=32 = two chained MM16: hi·y + (lo·x + C)) ----
    #pragma unroll
    for (int l = 0; l < 2; ++l){
      s4v ph0[QN], ph1[QN];
      #pragma unroll
      for (int q = 0; q < QN; ++q){ ph0[q] = pk2b(mkpk<false>(h0[q])); ph1[q] = pk2b(mkpk<false>(h1[q])); }
      f4v m0[QN], m1[QN];
      { A32 A = ld16(l);
        #pragma unroll
        for (int q = 0; q < QN; ++q){
          m0[q] = MM16(A.hi, ph1[q], MM16(A.lo, ph0[q], eC[l][q]));
          m1[q] = MM16(A.hi, ph0[q], MM16(A.lo, ph1[q], eC[l][q])); } }
      f4v g0[QN], g1[QN];
      { s4v A = ld8(7+l); f4v C = ldc(7+l);
        #pragma unroll
        for (int q = 0; q < QN; ++q){
          g0[q] = MM16(A, pk2b(mkpk<true>(m0[q])), C);
          g1[q] = MM16(A, pk2b(mkpk<true>(m1[q])), C); } }
      f4v u0[QN], u1[QN];
      { A32 A = ld16(2+l); f4v C = ldc(9+l);
        #pragma unroll
        for (int q = 0; q < QN; ++q){
          u0[q] = MM16(A.hi, pk2b(mkpk<false>(g0[q])), MM16(A.lo, ph0[q], C));
          u1[q] = MM16(A.hi, pk2b(mkpk<false>(g1[q])), MM16(A.lo, ph1[q], C)); } }
      { s4v A = ld8(9+l); f4v C = ldc(11+l);
        #pragma unroll
        for (int q = 0; q < QN; ++q){
          h0[q] = h0[q] + MM16(A, pk2b(mkpk<true>(u0[q])), C);
          h1[q] = h1[q] + MM16(A, pk2b(mkpk<true>(u1[q])), C); } }
    }

    // ---- classifier (0.5 pre-folded into the aCl fragment) ----
    { s4v A = ld8(4); f4v C = ldc(4); f4v w2v = ldc(13);
      #pragma unroll
      for (int q = 0; q < QN; ++q){
        f4v tc = MM16(A, pk2b(mkpk<false>(h0[q] + h1[q])), C);
        float part = fmaxf(tc[0],0.f)*w2v[0] + fmaxf(tc[1],0.f)*w2v[1]
                   + fmaxf(tc[2],0.f)*w2v[2] + fmaxf(tc[3],0.f)*w2v[3];
        part = qsum(part);
        int e = (QN*it + q)*16 + c;
        if (lane < 16 && e < B) out[e] = part + cb2;
      } }

    #pragma unroll
    for (int q = 0; q < QN; ++q){ nfe[q] = nfeN[q]; di[q]=diN[q]; zz[q]=zzN[q]; sp[q]=spN[q]; }
  }
}

extern "C" void kernel_launch(void* const* d_in, const int* in_sizes, int n_in,
                              void* d_out, int out_size, void* d_ws, size_t ws_size,
                              hipStream_t stream) {
  const float* nf    = (const float*)d_in[0];
  const float* dist  = (const float*)d_in[1];
  const float* dz    = (const float*)d_in[2];
  const float* s2p   = (const float*)d_in[3];
  const float* neW1  = (const float*)d_in[4];
  const float* neb1  = (const float*)d_in[5];
  const float* neW2  = (const float*)d_in[6];
  const float* neb2  = (const float*)d_in[7];
  const float* eeW1  = (const float*)d_in[8];
  const float* eeb1  = (const float*)d_in[9];
  const float* eeW2  = (const float*)d_in[10];
  const float* eeb2  = (const float*)d_in[11];
  const float* msgW1 = (const float*)d_in[12];
  const float* msgb1 = (const float*)d_in[13];
  const float* msgW2 = (const float*)d_in[14];
  const float* msgb2 = (const float*)d_in[15];
  const float* updW1 = (const float*)d_in[16];
  const float* updb1 = (const float*)d_in[17];
  const float* updW2 = (const float*)d_in[18];
  const float* updb2 = (const float*)d_in[19];
  const float* clsW1 = (const float*)d_in[20];
  const float* clsb1 = (const float*)d_in[21];
  const float* clsW2 = (const float*)d_in[22];
  const float* clsb2 = (const float*)d_in[23];

  const int B = in_sizes[1];
  const int ngroups = (B + 15) / 16;
  const int niters  = (ngroups + QN - 1) / QN;  // 6 groups per wave-iteration
  // R19-proven grid shape: 1024 blocks x 4 waves; grid-stride covers tail.
  int blocks = 1024;
  if (blocks * 4 > niters) blocks = (niters + 3) / 4;
  const int nwaves = blocks * 4;

  egnn_i6<<<blocks, 256, 0, stream>>>(
      nf, dist, dz, s2p,
      neW1, neb1, neW2, neb2,
      eeW1, eeb1, eeW2, eeb2,
      msgW1, msgb1, msgW2, msgb2,
      updW1, updb1, updW2, updb2,
      clsW1, clsb1, clsW2, clsb2,
      (float*)d_out, B, niters, nwaves);
}

// Round 26
// 51.884 us; speedup vs baseline: 1.2425x; 1.0103x over previous
//
#include <hip/hip_runtime.h>
#include <hip/hip_bf16.h>

typedef __attribute__((ext_vector_type(8))) short    s8v;  // bf16x8 (packing only)
typedef __attribute__((ext_vector_type(4))) short    s4v;  // bf16x4 MFMA-16 operand (2 VGPRs)
typedef __attribute__((ext_vector_type(4))) float    f4v;  // fp32x4 MFMA C/D
typedef __attribute__((ext_vector_type(4))) unsigned u4v;
typedef __attribute__((ext_vector_type(2))) unsigned u2v;

#define PIN(x) asm volatile("" : "+v"(x))

__device__ __forceinline__ unsigned short bfu(float x){
  union { __hip_bfloat16 h; unsigned short u; } cv;
  cv.h = __float2bfloat16(x);
  return cv.u;
}
__device__ __forceinline__ unsigned pkbf(float lo, float hi){
  return (unsigned)bfu(lo) | ((unsigned)bfu(hi) << 16);
}
__device__ __forceinline__ s8v mkfrag(unsigned a, unsigned b, unsigned c_, unsigned d){
  u4v u = {a, b, c_, d};
  return __builtin_bit_cast(s8v, u);
}
// 16x16x16 bf16 MFMA: 2-reg A/B — the packed D-quad (p0,p1) IS the B operand
// (identity k-mapping; A[c][k]=W[k][c], no row permutation).  Verified R19.
__device__ __forceinline__ f4v MM16(s4v a, s4v b, f4v acc){
  return __builtin_amdgcn_mfma_f32_16x16x16bf16_1k(a, b, acc, 0, 0, 0);
}

// Packed D-quad: p0 = (row 4g, 4g+1), p1 = (row 4g+2, 4g+3) at col c.
struct Pk { unsigned p0, p1; };
template<bool RELU>
__device__ __forceinline__ Pk mkpk(f4v d){
  float a = d[0], b = d[1], c_ = d[2], e = d[3];
  if (RELU){ a = fmaxf(a,0.f); b = fmaxf(b,0.f); c_ = fmaxf(c_,0.f); e = fmaxf(e,0.f); }
  Pk r; r.p0 = pkbf(a, b); r.p1 = pkbf(c_, e); return r;
}
__device__ __forceinline__ s4v pk2b(Pk x){
  u2v u = {x.p0, x.p1};
  return __builtin_bit_cast(s4v, u);          // free: D-quad -> B operand
}
__device__ __forceinline__ s4v mk2(unsigned a, unsigned b){
  u2v u = {a, b};
  return __builtin_bit_cast(s4v, u);
}

// LDS packing content IDENTICAL to R12/R17/R19 (proven).
__device__ __forceinline__ s8v loadA16(const float* __restrict__ W, int K, int c, int g,
                                       float scale = 1.0f){
  int r0 = 4*g;
  unsigned u0 = pkbf(r0+0<K ? W[(r0+0)*16+c]*scale : 0.f, r0+1<K ? W[(r0+1)*16+c]*scale : 0.f);
  unsigned u1 = pkbf(r0+2<K ? W[(r0+2)*16+c]*scale : 0.f, r0+3<K ? W[(r0+3)*16+c]*scale : 0.f);
  return mkfrag(u0, u1, 0u, 0u);
}
__device__ __forceinline__ s8v loadA32(const float* __restrict__ W, int c, int g){
  int r0 = 4*g;
  unsigned u0 = pkbf(W[(r0+0)*16+c],      W[(r0+1)*16+c]);
  unsigned u1 = pkbf(W[(r0+2)*16+c],      W[(r0+3)*16+c]);
  unsigned u2 = pkbf(W[(16+r0+0)*16+c],   W[(16+r0+1)*16+c]);
  unsigned u3 = pkbf(W[(16+r0+2)*16+c],   W[(16+r0+3)*16+c]);
  return mkfrag(u0, u1, u2, u3);
}

__device__ __forceinline__ void pl32(unsigned &a, unsigned &b){
  asm("v_permlane32_swap_b32 %0, %1" : "+v"(a), "+v"(b));
}
__device__ __forceinline__ void pl16(unsigned &a, unsigned &b){
  asm("v_permlane16_swap_b32 %0, %1" : "+v"(a), "+v"(b));
}
__device__ __forceinline__ float qsum(float part){
  unsigned pu = __builtin_bit_cast(unsigned, part), pv = pu;
  pl16(pu, pv);
  part = __builtin_bit_cast(float, pu) + __builtin_bit_cast(float, pv);
  pu = __builtin_bit_cast(unsigned, part); pv = pu;
  pl32(pu, pv);
  return __builtin_bit_cast(float, pu) + __builtin_bit_cast(float, pv);
}

// ---- LDS weight cache layout (bytes identical to R12..R19) ----
#define R16B  (11*512)          // 8B-fragment region: 11 frags x 64 lanes x 8B
#define RBB   (R16B + 4*1024)   // 16B-fragment region: 4 frags x 64 lanes x 16B
#define LDSZ  (RBB + 14*64)     // bias region: 14 vectors x 16 floats

__global__ void __launch_bounds__(256, 2) egnn_m16(
    const float* __restrict__ nf,   const float* __restrict__ dist,
    const float* __restrict__ dz,   const float* __restrict__ s2p,
    const float* __restrict__ neW1, const float* __restrict__ neb1,
    const float* __restrict__ neW2, const float* __restrict__ neb2,
    const float* __restrict__ eeW1, const float* __restrict__ eeb1,
    const float* __restrict__ eeW2, const float* __restrict__ eeb2,
    const float* __restrict__ msgW1, const float* __restrict__ msgb1,
    const float* __restrict__ msgW2, const float* __restrict__ msgb2,
    const float* __restrict__ updW1, const float* __restrict__ updb1,
    const float* __restrict__ updW2, const float* __restrict__ updb2,
    const float* __restrict__ clsW1, const float* __restrict__ clsb1,
    const float* __restrict__ clsW2, const float* __restrict__ clsb2,
    float* __restrict__ out, int B, int niters, int nwaves)
{
  __shared__ __align__(16) char wl[LDSZ];
  const int tid  = threadIdx.x;
  const int lane = tid & 63;
  const int c = lane & 15;
  const int g = lane >> 4;

  // ---- one-time per-block weight packing into LDS (wave 0 only) ----
  if (tid < 64){
    auto st8 = [&](int j, s8v f){
      u4v u = __builtin_bit_cast(u4v, f);
      *reinterpret_cast<uint2*>(wl + j*512 + lane*8) = make_uint2(u[0], u[1]);
    };
    auto st16 = [&](int j, s8v f){
      *reinterpret_cast<u4v*>(wl + R16B + j*1024 + lane*16) = __builtin_bit_cast(u4v, f);
    };
    st8(0, loadA16(neW1,  2, c, g));
    st8(1, loadA16(neW2, 16, c, g));
    st8(2, loadA16(eeW1,  3, c, g));
    st8(3, loadA16(eeW2, 16, c, g));
    st8(4, loadA16(clsW1,16, c, g, 0.5f));       // fold node-mean 0.5
    #pragma unroll
    for (int l = 0; l < 2; ++l){
      st8(5+l,  loadA16(msgW1 + l*768 + 512, 16, c, g));  // ee rows 32..47
      st8(7+l,  loadA16(msgW2 + l*256, 16, c, g));
      st8(9+l,  loadA16(updW2 + l*256, 16, c, g));
      st16(l,   loadA32(msgW1 + l*768, c, g));            // concat rows 0..31
      st16(2+l, loadA32(updW1 + l*512, c, g));            // h rows, msg rows
    }
    if (lane < 16){
      float* bf = reinterpret_cast<float*>(wl + RBB);
      bf[ 0*16+lane] = neb1[lane];      bf[ 1*16+lane] = neb2[lane];
      bf[ 2*16+lane] = eeb1[lane];      bf[ 3*16+lane] = eeb2[lane];
      bf[ 4*16+lane] = clsb1[lane];
      bf[ 5*16+lane] = msgb1[lane];     bf[ 6*16+lane] = msgb1[16+lane];
      bf[ 7*16+lane] = msgb2[lane];     bf[ 8*16+lane] = msgb2[16+lane];
      bf[ 9*16+lane] = updb1[lane];     bf[10*16+lane] = updb1[16+lane];
      bf[11*16+lane] = updb2[lane];     bf[12*16+lane] = updb2[16+lane];
      bf[13*16+lane] = clsW2[lane];
    }
  }
  __syncthreads();

  const float cb2 = clsb2[0];          // wave-uniform -> SGPR
  const int gwave = blockIdx.x * 4 + (tid >> 6);

  int it = gwave;
  float4 nfe[4]; float di[4], zz[4], sp[4];
  #pragma unroll
  for (int q = 0; q < 4; ++q){ nfe[q] = make_float4(0,0,0,0); di[q]=zz[q]=sp[q]=0.f; }
  if (it < niters){
    #pragma unroll
    for (int q = 0; q < 4; ++q){
      int e = min((4*it + q)*16 + c, B-1);
      nfe[q] = *reinterpret_cast<const float4*>(nf + (size_t)e * 4);
      di[q] = dist[e]; zz[q] = dz[e]; sp[q] = s2p[e];
    }
  }

  #pragma unroll 1
  for (; it < niters; it += nwaves){
    // PINned offsets: keep the weight/bias ds_reads in-loop (R8 spill trap).
    int o8 = lane*8, o16 = lane*16, ob = g*16;
    PIN(o8); PIN(o16); PIN(ob);
    const char* w8  = wl + o8;
    const char* w16 = wl + R16B + o16;
    const char* wb  = wl + RBB + ob;
    auto ld8 = [&](int j){                    // 2-reg A operand, direct
      uint2 v = *reinterpret_cast<const uint2*>(w8 + j*512);
      return mk2(v.x, v.y);
    };
    struct A32 { s4v lo, hi; };
    auto ld16 = [&](int j){                   // K=32 A: lo/hi 2-reg halves
      u4v v = *reinterpret_cast<const u4v*>(w16 + j*1024);
      A32 r; r.lo = mk2(v[0], v[1]); r.hi = mk2(v[2], v[3]);
      return r;
    };
    auto ldc = [&](int j){
      return *reinterpret_cast<const f4v*>(wb + j*64);
    };

    // prefetch next iteration's inputs
    float4 nfeN[4]; float diN[4], zzN[4], spN[4];
    #pragma unroll
    for (int q = 0; q < 4; ++q){ nfeN[q] = nfe[q]; diN[q]=di[q]; zzN[q]=zz[q]; spN[q]=sp[q]; }
    const int nit = it + nwaves;
    if (nit < niters){
      #pragma unroll
      for (int q = 0; q < 4; ++q){
        int e = min((4*nit + q)*16 + c, B-1);
        nfeN[q] = *reinterpret_cast<const float4*>(nf + (size_t)e * 4);
        diN[q] = dist[e]; zzN[q] = dz[e]; spN[q] = s2p[e];
      }
    }

    // ---- input fragments (g==0 masks REQUIRED — junk*0 = NaN when junk
    //      encodes Inf/NaN; R10 lesson) ----
    s4v b0f[4], b1f[4], bef[4];
    #pragma unroll
    for (int q = 0; q < 4; ++q){
      b0f[q] = mk2(g==0 ? pkbf(nfe[q].x, nfe[q].y) : 0u, 0u);
      b1f[q] = mk2(g==0 ? pkbf(nfe[q].z, nfe[q].w) : 0u, 0u);
      bef[q] = mk2(g==0 ? pkbf(di[q], zz[q]) : 0u, g==0 ? pkbf(sp[q], 0.f) : 0u);
    }

    // ---- embeddings ----
    f4v t0[4], t1[4], te[4], h0[4], h1[4], ee[4];
    { s4v A = ld8(0); f4v C = ldc(0);
      #pragma unroll
      for (int q = 0; q < 4; ++q){ t0[q] = MM16(A, b0f[q], C); t1[q] = MM16(A, b1f[q], C); } }
    { s4v A = ld8(2); f4v C = ldc(2);
      #pragma unroll
      for (int q = 0; q < 4; ++q){ te[q] = MM16(A, bef[q], C); } }
    { s4v A = ld8(1); f4v C = ldc(1);
      #pragma unroll
      for (int q = 0; q < 4; ++q){
        h0[q] = MM16(A, pk2b(mkpk<true>(t0[q])), C);
        h1[q] = MM16(A, pk2b(mkpk<true>(t1[q])), C); } }
    s4v eeB[4];
    { s4v A = ld8(3); f4v C = ldc(3);
      #pragma unroll
      for (int q = 0; q < 4; ++q){ ee[q] = MM16(A, pk2b(mkpk<true>(te[q])), C); } }
    #pragma unroll
    for (int q = 0; q < 4; ++q){ eeB[q] = pk2b(mkpk<false>(ee[q])); }

    // ---- eC HOIST (R17, proven): off the h-dependent critical chain ----
    f4v eC[2][4];
    #pragma unroll
    for (int l = 0; l < 2; ++l){
      s4v A = ld8(5+l); f4v C = ldc(5+l);
      #pragma unroll
      for (int q = 0; q < 4; ++q){ eC[l][q] = MM16(A, eeB[q], C); }
    }

    // ---- message-passing layers (K=32 = two chained MM16: hi·y + (lo·x + C)) ----
    #pragma unroll
    for (int l = 0; l < 2; ++l){
      s4v ph0[4], ph1[4];
      #pragma unroll
      for (int q = 0; q < 4; ++q){ ph0[q] = pk2b(mkpk<false>(h0[q])); ph1[q] = pk2b(mkpk<false>(h1[q])); }
      f4v m0[4], m1[4];
      { A32 A = ld16(l);
        #pragma unroll
        for (int q = 0; q < 4; ++q){
          m0[q] = MM16(A.hi, ph1[q], MM16(A.lo, ph0[q], eC[l][q]));
          m1[q] = MM16(A.hi, ph0[q], MM16(A.lo, ph1[q], eC[l][q])); } }
      f4v g0[4], g1[4];
      { s4v A = ld8(7+l); f4v C = ldc(7+l);
        #pragma unroll
        for (int q = 0; q < 4; ++q){
          g0[q] = MM16(A, pk2b(mkpk<true>(m0[q])), C);
          g1[q] = MM16(A, pk2b(mkpk<true>(m1[q])), C); } }
      f4v u0[4], u1[4];
      { A32 A = ld16(2+l); f4v C = ldc(9+l);
        #pragma unroll
        for (int q = 0; q < 4; ++q){
          u0[q] = MM16(A.hi, pk2b(mkpk<false>(g0[q])), MM16(A.lo, ph0[q], C));
          u1[q] = MM16(A.hi, pk2b(mkpk<false>(g1[q])), MM16(A.lo, ph1[q], C)); } }
      { s4v A = ld8(9+l); f4v C = ldc(11+l);
        #pragma unroll
        for (int q = 0; q < 4; ++q){
          h0[q] = h0[q] + MM16(A, pk2b(mkpk<true>(u0[q])), C);
          h1[q] = h1[q] + MM16(A, pk2b(mkpk<true>(u1[q])), C); } }
    }

    // ---- classifier (0.5 pre-folded into the aCl fragment) ----
    { s4v A = ld8(4); f4v C = ldc(4); f4v w2v = ldc(13);
      #pragma unroll
      for (int q = 0; q < 4; ++q){
        f4v tc = MM16(A, pk2b(mkpk<false>(h0[q] + h1[q])), C);
        float part = fmaxf(tc[0],0.f)*w2v[0] + fmaxf(tc[1],0.f)*w2v[1]
                   + fmaxf(tc[2],0.f)*w2v[2] + fmaxf(tc[3],0.f)*w2v[3];
        part = qsum(part);
        int e = (4*it + q)*16 + c;
        if (lane < 16 && e < B) out[e] = part + cb2;
      } }

    #pragma unroll
    for (int q = 0; q < 4; ++q){ nfe[q] = nfeN[q]; di[q]=diN[q]; zz[q]=zzN[q]; sp[q]=spN[q]; }
  }
}

extern "C" void kernel_launch(void* const* d_in, const int* in_sizes, int n_in,
                              void* d_out, int out_size, void* d_ws, size_t ws_size,
                              hipStream_t stream) {
  const float* nf    = (const float*)d_in[0];
  const float* dist  = (const float*)d_in[1];
  const float* dz    = (const float*)d_in[2];
  const float* s2p   = (const float*)d_in[3];
  const float* neW1  = (const float*)d_in[4];
  const float* neb1  = (const float*)d_in[5];
  const float* neW2  = (const float*)d_in[6];
  const float* neb2  = (const float*)d_in[7];
  const float* eeW1  = (const float*)d_in[8];
  const float* eeb1  = (const float*)d_in[9];
  const float* eeW2  = (const float*)d_in[10];
  const float* eeb2  = (const float*)d_in[11];
  const float* msgW1 = (const float*)d_in[12];
  const float* msgb1 = (const float*)d_in[13];
  const float* msgW2 = (const float*)d_in[14];
  const float* msgb2 = (const float*)d_in[15];
  const float* updW1 = (const float*)d_in[16];
  const float* updb1 = (const float*)d_in[17];
  const float* updW2 = (const float*)d_in[18];
  const float* updb2 = (const float*)d_in[19];
  const float* clsW1 = (const float*)d_in[20];
  const float* clsb1 = (const float*)d_in[21];
  const float* clsW2 = (const float*)d_in[22];
  const float* clsb2 = (const float*)d_in[23];

  const int B = in_sizes[1];
  const int ngroups = (B + 15) / 16;
  const int niters  = (ngroups + 3) / 4;       // 4 groups per wave-iteration
  // R26 terminal: R19's verified-best config (ILP4, 1024 blocks, 4 iters/wave).
  int blocks = 1024;
  if (blocks * 4 > niters) blocks = (niters + 3) / 4;
  const int nwaves = blocks * 4;

  egnn_m16<<<blocks, 256, 0, stream>>>(
      nf, dist, dz, s2p,
      neW1, neb1, neW2, neb2,
      eeW1, eeb1, eeW2, eeb2,
      msgW1, msgb1, msgW2, msgb2,
      updW1, updb1, updW2, updb2,
      clsW1, clsb1, clsW2, clsb2,
      (float*)d_out, B, niters, nwaves);
}